// Round 8
// baseline (195.920 us; speedup 1.0000x reference)
//
#include <hip/hip_runtime.h>

typedef __attribute__((ext_vector_type(8))) short bf16x8;
typedef __attribute__((ext_vector_type(4))) short bf16x4;
typedef __attribute__((ext_vector_type(4))) float f32x4;
typedef unsigned short ushort_t;

#define B_ 4
#define H_ 8
#define N_ 2048
#define D_ 512
#define MAXREL 199   // MAX_REL-1
#define LOG2E 1.4426950408889634f

__device__ __forceinline__ ushort_t f2bf(float f) {
    union { float f; unsigned u; } v; v.f = f;
    unsigned r = v.u + 0x7fffu + ((v.u >> 16) & 1u);
    return (ushort_t)(r >> 16);
}
__device__ __forceinline__ float bf2f(ushort_t u) {
    union { unsigned u; float f; } v; v.u = ((unsigned)u) << 16;
    return v.f;
}
__device__ __forceinline__ float fexp2(float x) {
#if __has_builtin(__builtin_amdgcn_exp2f)
    return __builtin_amdgcn_exp2f(x);
#else
    return __expf(x * 0.6931471805599453f);
#endif
}
__device__ __forceinline__ unsigned cvt_pk_bf16(float lo, float hi) {
    unsigned r;
    asm("v_cvt_pk_bf16_f32 %0, %1, %2" : "=v"(r) : "v"(lo), "v"(hi));
    return r;
}
// async global->LDS, 16B per lane; lds dest = wave-uniform base + lane*16
__device__ __forceinline__ void gl_lds16(const ushort_t* g, ushort_t* l) {
    __builtin_amdgcn_global_load_lds(
        (const __attribute__((address_space(1))) void*)g,
        (__attribute__((address_space(3))) void*)l,
        16, 0, 0);
}

// ---------------- prep v3: layernorm (wave-per-row) | wtrans(Wqkv) | wtrans(Wout) ----------------
#define PREP_LN    2048                     // (B*N)/4 rows
#define PREP_WQ    768                      // (1536/32)*(512/32)
#define PREP_WO    256                      // (512/32)*(512/32)
__global__ __launch_bounds__(256) void prep_kernel(const float* __restrict__ x,
                                                   const float* __restrict__ gamma,
                                                   const float* __restrict__ beta,
                                                   ushort_t* __restrict__ xn,
                                                   const float* __restrict__ Wqkv,
                                                   ushort_t* __restrict__ WqkvT,
                                                   const float* __restrict__ Wout,
                                                   ushort_t* __restrict__ WoutT) {
    __shared__ float smem[32 * 33];
    const int blk = blockIdx.x;
    const int t = threadIdx.x;

    if (blk < PREP_LN) {
        // ---- LayerNorm: one 64-lane wave per row, float4 loads, butterfly reduce (verified r6) ----
        const int row = blk * 4 + (t >> 6);
        const int l = t & 63;
        const float* xr = x + (size_t)row * D_;
        float4 a = *(const float4*)&xr[l * 4];
        float4 c = *(const float4*)&xr[256 + l * 4];
        float s = (a.x + a.y) + (a.z + a.w) + (c.x + c.y) + (c.z + c.w);
        #pragma unroll
        for (int o = 1; o < 64; o <<= 1) s += __shfl_xor(s, o);
        float mu = s * (1.0f / D_);
        float dx0 = a.x - mu, dx1 = a.y - mu, dx2 = a.z - mu, dx3 = a.w - mu;
        float dy0 = c.x - mu, dy1 = c.y - mu, dy2 = c.z - mu, dy3 = c.w - mu;
        float s2 = dx0*dx0 + dx1*dx1 + dx2*dx2 + dx3*dx3
                 + dy0*dy0 + dy1*dy1 + dy2*dy2 + dy3*dy3;
        #pragma unroll
        for (int o = 1; o < 64; o <<= 1) s2 += __shfl_xor(s2, o);
        float rs = rsqrtf(s2 * (1.0f / D_) + 1e-5f);
        float4 g1 = *(const float4*)&gamma[l * 4];
        float4 g2 = *(const float4*)&gamma[256 + l * 4];
        float4 b1 = *(const float4*)&beta[l * 4];
        float4 b2 = *(const float4*)&beta[256 + l * 4];
        ushort_t* yr = xn + (size_t)row * D_;
        union { ushort_t us[4]; unsigned long long ll; } o1, o2;
        o1.us[0] = f2bf(dx0 * rs * g1.x + b1.x);
        o1.us[1] = f2bf(dx1 * rs * g1.y + b1.y);
        o1.us[2] = f2bf(dx2 * rs * g1.z + b1.z);
        o1.us[3] = f2bf(dx3 * rs * g1.w + b1.w);
        o2.us[0] = f2bf(dy0 * rs * g2.x + b2.x);
        o2.us[1] = f2bf(dy1 * rs * g2.y + b2.y);
        o2.us[2] = f2bf(dy2 * rs * g2.z + b2.z);
        o2.us[3] = f2bf(dy3 * rs * g2.w + b2.w);
        *(unsigned long long*)(yr + l * 4) = o1.ll;
        *(unsigned long long*)(yr + 256 + l * 4) = o2.ll;
    } else {
        // ---- weight transpose fp32 [K][Nn] -> bf16 [Nn][K] ----
        const float* W; ushort_t* Wt; int Nn, i;
        if (blk < PREP_LN + PREP_WQ) {
            i = blk - PREP_LN; W = Wqkv; Wt = WqkvT; Nn = 1536;
        } else {
            i = blk - (PREP_LN + PREP_WQ); W = Wout; Wt = WoutT; Nn = 512;
        }
        const int nb = Nn >> 5;
        const int bx = (i % nb) * 32, by = (i / nb) * 32;
        const int tx = t & 31, ty = t >> 5;
        float (*tile)[33] = (float(*)[33])smem;
        #pragma unroll
        for (int k = 0; k < 32; k += 8)
            tile[ty + k][tx] = W[(size_t)(by + ty + k) * Nn + bx + tx];
        __syncthreads();
        #pragma unroll
        for (int k = 0; k < 32; k += 8)
            Wt[(size_t)(bx + ty + k) * 512 + by + tx] = f2bf(tile[tx][ty + k]);
    }
}

// ---------------- QKV GEMM v3: 2-phase pipelined K-loop + concurrent bias-pack ----------------
// T3-minimal pipeline: double-buffered LDS, stage k+1 BEFORE compute of k, one barrier/step.
// V-blocks (which==2) get an LDS-restaged epilogue (256B-contiguous n-runs; kills 8B@4KB scatter).
#define QKV_BIAS_BLKS 512
__global__ __launch_bounds__(256) void gemm_qkv(const ushort_t* __restrict__ A,
                                                const ushort_t* __restrict__ Bt,
                                                ushort_t* __restrict__ qb,
                                                ushort_t* __restrict__ kb,
                                                ushort_t* __restrict__ vb,
                                                const float* __restrict__ rel,
                                                const int* __restrict__ mask,
                                                ushort_t* __restrict__ bp) {
    const int bid = blockIdx.x;
    const int t = threadIdx.x;

    if (bid < QKV_BIAS_BLKS) {
        // ---- bias+mask pack into [qt][jt][w][nt][quad][m16][k4] order, log2 domain ----
        const int base = bid * 8192;
        #pragma unroll
        for (int p = 0; p < 8; p++) {
            int idx = base + p * 1024 + t * 4;   // 4 consecutive m, same n
            int n = idx >> 11, m = idx & 2047;
            const int4 mv = *(const int4*)&mask[idx];
            union { ushort_t us[4]; unsigned long long ll; } pkv;
            #pragma unroll
            for (int j = 0; j < 4; j++) {
                int dl = n - (m + j);
                dl = dl < -MAXREL ? -MAXREL : (dl > MAXREL ? MAXREL : dl);
                int mj = (j == 0) ? mv.x : (j == 1) ? mv.y : (j == 2) ? mv.z : mv.w;
                float v = (mj == 0) ? -1e9f : rel[dl + MAXREL] * LOG2E;
                pkv.us[j] = f2bf(v);
            }
            int off = ((n >> 7) << 18) + ((m >> 6) << 13) + (((n >> 4) & 7) << 10)
                    + (((m >> 4) & 3) << 8) + (((m >> 2) & 3) << 6) + ((n & 15) << 2);
            *(unsigned long long*)(bp + off) = pkv.ll;
        }
        return;
    }

    __shared__ ushort_t As[2][4096];         // 16KB (also reused as v-restage buffer)
    __shared__ ushort_t Bs[2][4096];         // 16KB
    const int gid = bid - QKV_BIAS_BLKS;
    const int lane = t & 63, w = t >> 6;
    const int m16 = lane & 15, quad = lane >> 4;
    const int wr = w >> 1, wc = w & 1;
    const int r0 = (gid / 12) * 128, c0 = (gid % 12) * 128;

    const ushort_t* Ag = A  + (size_t)(r0 + (t >> 2)) * D_ + (t & 3) * 8;
    const ushort_t* Bg = Bt + (size_t)(c0 + (t >> 2)) * D_ + (t & 3) * 8;

    f32x4 acc[4][4];
    #pragma unroll
    for (int i = 0; i < 4; i++)
        #pragma unroll
        for (int j = 0; j < 4; j++) acc[i][j] = (f32x4){0.f, 0.f, 0.f, 0.f};

    // prologue: stage k0=0 into buf 0
    {
        ushort_t* AsW = As[0] + w * 512;
        ushort_t* BsW = Bs[0] + w * 512;
        gl_lds16(Ag, AsW);
        gl_lds16(Ag + (size_t)64 * D_, AsW + 2048);
        gl_lds16(Bg, BsW);
        gl_lds16(Bg + (size_t)64 * D_, BsW + 2048);
    }
    __syncthreads();

    for (int k0 = 0; k0 < D_; k0 += 32) {
        const int buf = (k0 >> 5) & 1;
        if (k0 + 32 < D_) {                  // issue next-step loads BEFORE compute
            ushort_t* AsW = As[buf ^ 1] + w * 512;
            ushort_t* BsW = Bs[buf ^ 1] + w * 512;
            gl_lds16(Ag + k0 + 32, AsW);
            gl_lds16(Ag + k0 + 32 + (size_t)64 * D_, AsW + 2048);
            gl_lds16(Bg + k0 + 32, BsW);
            gl_lds16(Bg + k0 + 32 + (size_t)64 * D_, BsW + 2048);
        }
        bf16x8 af[4], bfr[4];
        #pragma unroll
        for (int rt = 0; rt < 4; rt++)
            af[rt] = *(const bf16x8*)(As[buf] + (wr * 64 + rt * 16 + m16) * 32 + quad * 8);
        #pragma unroll
        for (int ct = 0; ct < 4; ct++)
            bfr[ct] = *(const bf16x8*)(Bs[buf] + (wc * 64 + ct * 16 + m16) * 32 + quad * 8);
        #pragma unroll
        for (int rt = 0; rt < 4; rt++)
            #pragma unroll
            for (int ct = 0; ct < 4; ct++)
                acc[rt][ct] = __builtin_amdgcn_mfma_f32_16x16x32_bf16(af[rt], bfr[ct], acc[rt][ct], 0, 0, 0);
        __syncthreads();                     // one barrier/step: drains loads into buf^1
    }

    const int b_blk = r0 >> 11, n_base = r0 & 2047;
    if ((c0 >> 9) == 2) {
        // ---- V epilogue: LDS restage (r6-verified v-phase), 256B-contiguous stores along n ----
        ushort_t* SH = As[0];                // 16KB contiguous
        #pragma unroll
        for (int ph = 0; ph < 2; ph++) {
            if (ph) __syncthreads();
            if (wc == ph) {
                #pragma unroll
                for (int ct = 0; ct < 4; ct++) {
                    int dcol = ct * 16 + m16;
                    #pragma unroll
                    for (int rt = 0; rt < 4; rt++) {
                        int nl = wr * 64 + rt * 16 + quad * 4;
                        union { ushort_t us[4]; unsigned long long ll; } pkv;
                        #pragma unroll
                        for (int r = 0; r < 4; r++) pkv.us[r] = f2bf(acc[rt][ct][r]);
                        *(unsigned long long*)(&SH[dcol * 128 + (nl ^ ((dcol & 7) << 3))]) = pkv.ll;
                    }
                }
            }
            __syncthreads();
            int h = ((c0 + ph * 64) >> 6) & 7;
            #pragma unroll
            for (int p = 0; p < 4; p++) {
                int dr = p * 16 + (t >> 4);
                int n0 = (t & 15) * 8;
                bf16x8 vv = *(const bf16x8*)&SH[dr * 128 + (n0 ^ ((dr & 7) << 3))];
                *(bf16x8*)(vb + ((size_t)(b_blk * H_ + h) * 64 + dr) * N_ + n_base + n0) = vv;
            }
        }
    } else {
        // ---- q/k epilogue (unchanged, 32B-run scalar stores) ----
        #pragma unroll
        for (int ct = 0; ct < 4; ct++) {
            int cc = c0 + wc * 64 + ct * 16;
            int which = cc >> 9;
            int h = (cc >> 6) & 7;
            int d = (cc & 63) + m16;
            #pragma unroll
            for (int rt = 0; rt < 4; rt++) {
                int rowb = r0 + wr * 64 + rt * 16 + quad * 4;
                int b = rowb >> 11, n0 = rowb & 2047;
                if (which == 0) {
                    #pragma unroll
                    for (int r = 0; r < 4; r++)
                        qb[((size_t)((b * H_ + h) * N_ + n0 + r)) * 64 + d] = f2bf(acc[rt][ct][r] * (0.125f * LOG2E));
                } else {
                    #pragma unroll
                    for (int r = 0; r < 4; r++)
                        kb[((size_t)((b * H_ + h) * N_ + n0 + r)) * 64 + d] = f2bf(acc[rt][ct][r]);
                }
            }
        }
    }
}

// ---------------- Out-proj v2: 2-phase pipelined K-loop (same T3-minimal structure) ----------------
__global__ __launch_bounds__(256) void gemm_out(const ushort_t* __restrict__ A,
                                                const ushort_t* __restrict__ Bt,
                                                const float* __restrict__ bias,
                                                float* __restrict__ C) {
    __shared__ ushort_t As[2][2048];
    __shared__ ushort_t Bs[2][4096];
    const int t = threadIdx.x;
    const int lane = t & 63, w = t >> 6;
    const int m16 = lane & 15, quad = lane >> 4;
    const int wr = w >> 1, wc = w & 1;        // wave tile: 32 rows x 64 cols
    const int r0 = blockIdx.y * 64, c0 = blockIdx.x * 128;

    const ushort_t* Ag = A  + (size_t)(r0 + (t >> 2)) * D_ + (t & 3) * 8;
    const ushort_t* Bg = Bt + (size_t)(c0 + (t >> 2)) * D_ + (t & 3) * 8;

    f32x4 acc[2][4];
    #pragma unroll
    for (int i = 0; i < 2; i++)
        #pragma unroll
        for (int j = 0; j < 4; j++) acc[i][j] = (f32x4){0.f, 0.f, 0.f, 0.f};

    {
        ushort_t* AsW = As[0] + w * 512;     // only waves' first half used for A (64 rows)
        ushort_t* BsW = Bs[0] + w * 512;
        if (w < 2) gl_lds16(Ag, As[0] + w * 1024 + (lane & 63) * 0 + w * 0 + (t & 255) * 0 + w * 1024), (void)0;
        // NOTE: A is 64 rows x 32 k = 2048 ushorts = 4KB; stage with waves 0-1 pattern below.
        (void)AsW; (void)BsW;
    }
    // -- restart staging cleanly (A: 2 waves' worth; B: 4 waves' worth) --
    {
        if (t < 128) gl_lds16(Ag, As[0] + (t >> 6) * 1024 + 0 * 512 + ((t >> 6) ? 512 : 0) * 0 + (t & 63) * 0 + (t >> 6) * 0 + ((t & 127) >> 6) * 0 + 0), (void)0;
    }
    // The two blocks above are no-ops kept minimal; do explicit correct staging:
    __syncthreads();
    {
        // A tile: rows r0..r0+63, 64 rows * 64B = 4KB -> threads 0..255 stage 16B each
        gl_lds16(Ag, As[0] + w * 512);       // threads t: row r0+(t>>2), bytes (t&3)*16
        gl_lds16(Bg, Bs[0] + w * 512);
        gl_lds16(Bg + (size_t)64 * D_, Bs[0] + w * 512 + 2048);
    }
    __syncthreads();

    for (int k0 = 0; k0 < D_; k0 += 32) {
        const int buf = (k0 >> 5) & 1;
        if (k0 + 32 < D_) {
            gl_lds16(Ag + k0 + 32, As[buf ^ 1] + w * 512);
            gl_lds16(Bg + k0 + 32, Bs[buf ^ 1] + w * 512);
            gl_lds16(Bg + k0 + 32 + (size_t)64 * D_, Bs[buf ^ 1] + w * 512 + 2048);
        }
        bf16x8 af[2], bfr[4];
        #pragma unroll
        for (int mf = 0; mf < 2; mf++)
            af[mf] = *(const bf16x8*)(As[buf] + (wr * 32 + mf * 16 + m16) * 32 + quad * 8);
        #pragma unroll
        for (int nt = 0; nt < 4; nt++)
            bfr[nt] = *(const bf16x8*)(Bs[buf] + (wc * 64 + nt * 16 + m16) * 32 + quad * 8);
        #pragma unroll
        for (int mf = 0; mf < 2; mf++)
            #pragma unroll
            for (int nt = 0; nt < 4; nt++)
                acc[mf][nt] = __builtin_amdgcn_mfma_f32_16x16x32_bf16(af[mf], bfr[nt], acc[mf][nt], 0, 0, 0);
        __syncthreads();
    }

    #pragma unroll
    for (int mf = 0; mf < 2; mf++) {
        #pragma unroll
        for (int nt = 0; nt < 4; nt++) {
            int col = c0 + wc * 64 + nt * 16 + m16;
            int row0 = r0 + wr * 32 + mf * 16 + quad * 4;
            float bv = bias[col];
            #pragma unroll
            for (int r = 0; r < 4; r++)
                C[(size_t)(row0 + r) * 512 + col] = acc[mf][nt][r] + bv;
        }
    }
}

// ---------------- MFMA flash attention v10 (unchanged, verified 55-57us) ----------------
#define ATTN_TILE(JT, KCUR, VCUR, KNXT, VNXT, BCUR, BNXT)                              \
  {                                                                                    \
    const int jt = (JT);                                                               \
    const int buf = jt & 1;                                                            \
    if (jt + 2 < 32) {                                                                 \
      KNXT = *(const bf16x8*)(kgbase + (size_t)((jt + 2) * 64 + srow) * 64 + scb * 8); \
      VNXT = *(const bf16x8*)(vgbase + (size_t)srow * N_ + (jt + 2) * 64 + scb * 8);   \
    }                                                                                  \
    if (jt + 1 < 32) {                                                                 \
      _Pragma("unroll")                                                                \
      for (int nt = 0; nt < 4; nt++)                                                   \
        BNXT[nt] = *(const bf16x4*)(bpb + ((jt + 1) << 13) + (nt << 8));               \
    }                                                                                  \
    unsigned pk[8];                                                                    \
    __builtin_amdgcn_s_setprio(1);                                                     \
    _Pragma("unroll")                                                                  \
    for (int nt = 0; nt < 4; nt++) {                                                   \
      f32x4 a2;                                                                        \
      _Pragma("unroll")                                                                \
      for (int r = 0; r < 4; r++) a2[r] = bf2f((ushort_t)BCUR[nt][r]);                 \
      int kr = nt * 16 + m16;                                                          \
      bf16x8 kf0 = *(const bf16x8*)(&Ks[buf][kr * 64 + ((quad) ^ (kr & 7)) * 8]);      \
      bf16x8 kf1 = *(const bf16x8*)(&Ks[buf][kr * 64 + ((quad + 4) ^ (kr & 7)) * 8]);  \
      a2 = __builtin_amdgcn_mfma_f32_16x16x32_bf16(kf0, qa0, a2, 0, 0, 0);             \
      a2 = __builtin_amdgcn_mfma_f32_16x16x32_bf16(kf1, qa1, a2, 0, 0, 0);             \
      float p0 = fexp2(a2[0]), p1 = fexp2(a2[1]);                                      \
      float p2 = fexp2(a2[2]), p3 = fexp2(a2[3]);                                      \
      rsum += (p0 + p1) + (p2 + p3);                                                   \
      pk[nt * 2]     = cvt_pk_bf16(p0, p1);                                            \
      pk[nt * 2 + 1] = cvt_pk_bf16(p2, p3);                                            \
    }                                                                                  \
    __builtin_amdgcn_s_setprio(0);                                                     \
    _Pragma("unroll")                                                                  \
    for (int i = 0; i < 4; i++) {                                                      \
      int chunk = 2 * i + (quad >> 1);                                                 \
      union { unsigned uu[2]; unsigned long long ll; } wrp;                            \
      wrp.uu[0] = pk[2 * i]; wrp.uu[1] = pk[2 * i + 1];                                \
      *(unsigned long long*)(pw + m16 * 64 + ((chunk ^ (m16 & 7)) << 3)                \
                             + (quad & 1) * 4) = wrp.ll;                               \
    }                                                                                  \
    bf16x8 pa0 = *(const bf16x8*)(pw + m16 * 64 + ((quad ^ (m16 & 7)) << 3));          \
    bf16x8 pa1 = *(const bf16x8*)(pw + m16 * 64 + (((quad + 4) ^ (m16 & 7)) << 3));    \
    __builtin_amdgcn_s_setprio(1);                                                     \
    _Pragma("unroll")                                                                  \
    for (int nt = 0; nt < 4; nt++) {                                                   \
      int d = nt * 16 + m16;                                                           \
      bf16x8 vf0 = *(const bf16x8*)(&Vs[buf][d * 64 + ((quad) ^ (d & 7)) * 8]);        \
      bf16x8 vf1 = *(const bf16x8*)(&Vs[buf][d * 64 + ((quad + 4) ^ (d & 7)) * 8]);    \
      o[nt] = __builtin_amdgcn_mfma_f32_16x16x32_bf16(pa0, vf0, o[nt], 0, 0, 0);       \
      o[nt] = __builtin_amdgcn_mfma_f32_16x16x32_bf16(pa1, vf1, o[nt], 0, 0, 0);       \
    }                                                                                  \
    __builtin_amdgcn_s_setprio(0);                                                     \
    if (jt + 1 < 32) {                                                                 \
      *(bf16x8*)(&Ks[buf ^ 1][soff]) = KCUR;                                           \
      *(bf16x8*)(&Vs[buf ^ 1][soff]) = VCUR;                                           \
    }                                                                                  \
    __syncthreads();                                                                   \
  }

__global__ __launch_bounds__(512, 4) void attn_mfma(const ushort_t* __restrict__ qb,
                                                    const ushort_t* __restrict__ kb,
                                                    const ushort_t* __restrict__ vb,
                                                    const ushort_t* __restrict__ bp,
                                                    ushort_t* __restrict__ attn) {
    __shared__ ushort_t Ks[2][64 * 64];      // [buf][key][d] swizzled, 8KB each
    __shared__ ushort_t Vs[2][64 * 64];      // [buf][d][key] swizzled, 8KB each
    __shared__ ushort_t p_s[8][16 * 64];     // [wave][qrow][key] swizzled, 16KB

    const int t = threadIdx.x;
    const int w = t >> 6, lane = t & 63;
    const int m16 = lane & 15, quad = lane >> 4;
    const int id = blockIdx.x;
    const int bh = id & 31;                  // XCD = id%8 = bh%8 (heuristic)
    const int qt = id >> 5;
    const int b = bh >> 3, h = bh & 7;
    const int n0w = qt * 128 + w * 16;

    // staging: thread stages exactly one 8-elem chunk of K and of V per tile
    const int srow = t >> 3, scb = t & 7;
    const int soff = srow * 64 + (scb ^ (srow & 7)) * 8;
    const ushort_t* kgbase = kb + ((size_t)bh * N_) * 64;   // [key][d]
    const ushort_t* vgbase = vb + ((size_t)bh * 64) * N_;   // [d][key]

    // Q frags (one 16-row m-frag per wave)
    const ushort_t* qpb = qb + ((size_t)(bh * N_ + n0w + m16)) * 64 + quad * 8;
    bf16x8 qa0 = *(const bf16x8*)(qpb);
    bf16x8 qa1 = *(const bf16x8*)(qpb + 32);

    // bias packed [qt][jt][w][nt][quad][m16][k4]; per phase the 16 m16-lanes read 128B contiguous
    const ushort_t* bpb = bp + ((size_t)qt << 18) + (w << 10) + (quad << 6) + (m16 << 2);

    // prologue: stage tile 0 into buf 0; prefetch tile 1 (regs) and bias jt=0 (regs)
    *(bf16x8*)(&Ks[0][soff]) = *(const bf16x8*)(kgbase + (size_t)srow * 64 + scb * 8);
    *(bf16x8*)(&Vs[0][soff]) = *(const bf16x8*)(vgbase + (size_t)srow * N_ + scb * 8);
    bf16x8 kA = *(const bf16x8*)(kgbase + (size_t)(64 + srow) * 64 + scb * 8);
    bf16x8 vA = *(const bf16x8*)(vgbase + (size_t)srow * N_ + 64 + scb * 8);
    bf16x8 kB, vB;
    bf16x4 bA[4], bB[4];
    #pragma unroll
    for (int nt = 0; nt < 4; nt++) bA[nt] = *(const bf16x4*)(bpb + (nt << 8));
    __syncthreads();

    f32x4 o[4];
    #pragma unroll
    for (int nt = 0; nt < 4; nt++) o[nt] = (f32x4){0.f, 0.f, 0.f, 0.f};
    float rsum = 0.f;

    ushort_t* pw = p_s[w];

    for (int jt2 = 0; jt2 < 16; jt2++) {
        ATTN_TILE(2 * jt2,     kA, vA, kB, vB, bA, bB);
        ATTN_TILE(2 * jt2 + 1, kB, vB, kA, vA, bB, bA);
    }

    // ---- row-sum: lane holds partial for qrow=m16 over its 16 key-residues; reduce across quads ----
    rsum += __shfl_xor(rsum, 16);
    rsum += __shfl_xor(rsum, 32);

    // ---- normalize + store: o[nt][r] is (qrow=quad*4+r, d=nt*16+m16) ----
    #pragma unroll
    for (int r = 0; r < 4; r++) {
        float inv = 1.0f / __shfl(rsum, quad * 4 + r);
        int n = n0w + quad * 4 + r;
        ushort_t* orow = attn + ((size_t)(b * N_ + n)) * 512 + h * 64 + m16;
        #pragma unroll
        for (int nt = 0; nt < 4; nt++) orow[nt * 16] = f2bf(o[nt][r] * inv);
    }
}

extern "C" void kernel_launch(void* const* d_in, const int* in_sizes, int n_in,
                              void* d_out, int out_size, void* d_ws, size_t ws_size,
                              hipStream_t stream) {
    const float* x     = (const float*)d_in[0];
    const float* gamma = (const float*)d_in[1];
    const float* beta  = (const float*)d_in[2];
    const float* Wqkv  = (const float*)d_in[3];
    const float* Wout  = (const float*)d_in[4];
    const float* bout  = (const float*)d_in[5];
    const float* rel   = (const float*)d_in[6];
    const int*   mask  = (const int*)d_in[7];
    float* out = (float*)d_out;

    char* wsb = (char*)d_ws;
    ushort_t* xn    = (ushort_t*)(wsb);                    //  8 MB
    ushort_t* attnb = (ushort_t*)(wsb + ( 8u << 20));      //  8 MB
    ushort_t* qb    = (ushort_t*)(wsb + (16u << 20));      //  8 MB
    ushort_t* kb    = (ushort_t*)(wsb + (24u << 20));      //  8 MB
    ushort_t* vb    = (ushort_t*)(wsb + (32u << 20));      //  8 MB
    ushort_t* WqkvT = (ushort_t*)(wsb + (40u << 20));      //  1.5 MB
    ushort_t* WoutT = (ushort_t*)(wsb + (42u << 20));      //  0.5 MB
    ushort_t* bp    = (ushort_t*)(wsb + (44u << 20));      //  8 MB

    // 1. prep: layernorm + both weight transposes
    prep_kernel<<<PREP_LN + PREP_WQ + PREP_WO, 256, 0, stream>>>(
        x, gamma, beta, xn, Wqkv, WqkvT, Wout, WoutT);

    // 2. QKV projection (pipelined MFMA + global_load_lds) + concurrent bias-pack blocks
    gemm_qkv<<<QKV_BIAS_BLKS + 768, 256, 0, stream>>>(xn, WqkvT, qb, kb, vb, rel, mask, bp);

    // 3. MFMA flash attention v10 -> bf16
    attn_mfma<<<512, 512, 0, stream>>>(qb, kb, vb, bp, attnb);

    // 4. output projection + bias (pipelined MFMA + global_load_lds) -> fp32
    gemm_out<<<dim3(512 / 128, 8192 / 64), 256, 0, stream>>>(attnb, WoutT, bout, out);
}

// Round 9
// 195.280 us; speedup vs baseline: 1.0033x; 1.0033x over previous
//
#include <hip/hip_runtime.h>

typedef __attribute__((ext_vector_type(8))) short bf16x8;
typedef __attribute__((ext_vector_type(4))) short bf16x4;
typedef __attribute__((ext_vector_type(4))) float f32x4;
typedef unsigned short ushort_t;

#define B_ 4
#define H_ 8
#define N_ 2048
#define D_ 512
#define MAXREL 199   // MAX_REL-1
#define LOG2E 1.4426950408889634f

__device__ __forceinline__ ushort_t f2bf(float f) {
    union { float f; unsigned u; } v; v.f = f;
    unsigned r = v.u + 0x7fffu + ((v.u >> 16) & 1u);
    return (ushort_t)(r >> 16);
}
__device__ __forceinline__ float bf2f(ushort_t u) {
    union { unsigned u; float f; } v; v.u = ((unsigned)u) << 16;
    return v.f;
}
__device__ __forceinline__ float fexp2(float x) {
#if __has_builtin(__builtin_amdgcn_exp2f)
    return __builtin_amdgcn_exp2f(x);
#else
    return __expf(x * 0.6931471805599453f);
#endif
}
__device__ __forceinline__ unsigned cvt_pk_bf16(float lo, float hi) {
    unsigned r;
    asm("v_cvt_pk_bf16_f32 %0, %1, %2" : "=v"(r) : "v"(lo), "v"(hi));
    return r;
}
// async global->LDS, 16B per lane; lds dest = wave-uniform base + lane*16
__device__ __forceinline__ void gl_lds16(const ushort_t* g, ushort_t* l) {
    __builtin_amdgcn_global_load_lds(
        (const __attribute__((address_space(1))) void*)g,
        (__attribute__((address_space(3))) void*)l,
        16, 0, 0);
}

// ---------------- prep v3: layernorm (wave-per-row) | wtrans(Wqkv) | wtrans(Wout) ----------------
#define PREP_LN    2048                     // (B*N)/4 rows
#define PREP_WQ    768                      // (1536/32)*(512/32)
#define PREP_WO    256                      // (512/32)*(512/32)
__global__ __launch_bounds__(256) void prep_kernel(const float* __restrict__ x,
                                                   const float* __restrict__ gamma,
                                                   const float* __restrict__ beta,
                                                   ushort_t* __restrict__ xn,
                                                   const float* __restrict__ Wqkv,
                                                   ushort_t* __restrict__ WqkvT,
                                                   const float* __restrict__ Wout,
                                                   ushort_t* __restrict__ WoutT) {
    __shared__ float smem[32 * 33];
    const int blk = blockIdx.x;
    const int t = threadIdx.x;

    if (blk < PREP_LN) {
        // ---- LayerNorm: one 64-lane wave per row, float4 loads, butterfly reduce (verified r6) ----
        const int row = blk * 4 + (t >> 6);
        const int l = t & 63;
        const float* xr = x + (size_t)row * D_;
        float4 a = *(const float4*)&xr[l * 4];
        float4 c = *(const float4*)&xr[256 + l * 4];
        float s = (a.x + a.y) + (a.z + a.w) + (c.x + c.y) + (c.z + c.w);
        #pragma unroll
        for (int o = 1; o < 64; o <<= 1) s += __shfl_xor(s, o);
        float mu = s * (1.0f / D_);
        float dx0 = a.x - mu, dx1 = a.y - mu, dx2 = a.z - mu, dx3 = a.w - mu;
        float dy0 = c.x - mu, dy1 = c.y - mu, dy2 = c.z - mu, dy3 = c.w - mu;
        float s2 = dx0*dx0 + dx1*dx1 + dx2*dx2 + dx3*dx3
                 + dy0*dy0 + dy1*dy1 + dy2*dy2 + dy3*dy3;
        #pragma unroll
        for (int o = 1; o < 64; o <<= 1) s2 += __shfl_xor(s2, o);
        float rs = rsqrtf(s2 * (1.0f / D_) + 1e-5f);
        float4 g1 = *(const float4*)&gamma[l * 4];
        float4 g2 = *(const float4*)&gamma[256 + l * 4];
        float4 b1 = *(const float4*)&beta[l * 4];
        float4 b2 = *(const float4*)&beta[256 + l * 4];
        ushort_t* yr = xn + (size_t)row * D_;
        union { ushort_t us[4]; unsigned long long ll; } o1, o2;
        o1.us[0] = f2bf(dx0 * rs * g1.x + b1.x);
        o1.us[1] = f2bf(dx1 * rs * g1.y + b1.y);
        o1.us[2] = f2bf(dx2 * rs * g1.z + b1.z);
        o1.us[3] = f2bf(dx3 * rs * g1.w + b1.w);
        o2.us[0] = f2bf(dy0 * rs * g2.x + b2.x);
        o2.us[1] = f2bf(dy1 * rs * g2.y + b2.y);
        o2.us[2] = f2bf(dy2 * rs * g2.z + b2.z);
        o2.us[3] = f2bf(dy3 * rs * g2.w + b2.w);
        *(unsigned long long*)(yr + l * 4) = o1.ll;
        *(unsigned long long*)(yr + 256 + l * 4) = o2.ll;
    } else {
        // ---- weight transpose fp32 [K][Nn] -> bf16 [Nn][K] ----
        const float* W; ushort_t* Wt; int Nn, i;
        if (blk < PREP_LN + PREP_WQ) {
            i = blk - PREP_LN; W = Wqkv; Wt = WqkvT; Nn = 1536;
        } else {
            i = blk - (PREP_LN + PREP_WQ); W = Wout; Wt = WoutT; Nn = 512;
        }
        const int nb = Nn >> 5;
        const int bx = (i % nb) * 32, by = (i / nb) * 32;
        const int tx = t & 31, ty = t >> 5;
        float (*tile)[33] = (float(*)[33])smem;
        #pragma unroll
        for (int k = 0; k < 32; k += 8)
            tile[ty + k][tx] = W[(size_t)(by + ty + k) * Nn + bx + tx];
        __syncthreads();
        #pragma unroll
        for (int k = 0; k < 32; k += 8)
            Wt[(size_t)(bx + ty + k) * 512 + by + tx] = f2bf(tile[tx][ty + k]);
    }
}

// ---------------- QKV GEMM v4: pipelined K-loop + concurrent bias-pack v3 ----------------
// Bias-pack v3: block owns 16 consecutive n x 2048 m; per-wave LDS transpose [16][17] ull
// (bank-conflict-free both sides, no barriers) -> each wave dumps 2KB fully-contiguous bp
// regions. Full-line writes: kills the 4x write amplification (57 -> ~34 MB WRITE_SIZE).
#define QKV_BIAS_BLKS 128
__global__ __launch_bounds__(256) void gemm_qkv(const ushort_t* __restrict__ A,
                                                const ushort_t* __restrict__ Bt,
                                                ushort_t* __restrict__ qb,
                                                ushort_t* __restrict__ kb,
                                                ushort_t* __restrict__ vb,
                                                const float* __restrict__ rel,
                                                const int* __restrict__ mask,
                                                ushort_t* __restrict__ bp) {
    __shared__ ushort_t As[2][4096];         // 16KB (bias branch aliases this as transpose scratch)
    __shared__ ushort_t Bs[2][4096];         // 16KB
    const int bid = blockIdx.x;
    const int t = threadIdx.x;

    if (bid < QKV_BIAS_BLKS) {
        // ---- bias+mask pack, line-filling writes via per-wave LDS transpose ----
        unsigned long long (*lds_t)[16][17] = (unsigned long long(*)[16][17])As;  // 8.7KB of As
        const int w = t >> 6, l = t & 63;
        const int n0 = bid * 16;
        const int m4 = l & 15;
        const int m4d = ((l >> 4) << 2) | ((l >> 2) & 3);
        const size_t rbase0 = (((size_t)(bid >> 3)) << 18) + (((size_t)(bid & 7)) << 10);
        #pragma unroll
        for (int i = 0; i < 8; i++) {
            const int jt = w + i * 4;
            const int m = jt * 64 + m4 * 4;
            #pragma unroll
            for (int s = 0; s < 4; s++) {
                const int nl = s * 4 + (l >> 4);
                const int n = n0 + nl;
                const int4 mv = *(const int4*)&mask[(size_t)n * 2048 + m];
                union { ushort_t us[4]; unsigned long long ll; } pkv;
                #pragma unroll
                for (int j = 0; j < 4; j++) {
                    int dl = n - (m + j);
                    dl = dl < -MAXREL ? -MAXREL : (dl > MAXREL ? MAXREL : dl);
                    int mj = (j == 0) ? mv.x : (j == 1) ? mv.y : (j == 2) ? mv.z : mv.w;
                    float v = (mj == 0) ? -1e9f : rel[dl + MAXREL] * LOG2E;
                    pkv.us[j] = f2bf(v);
                }
                lds_t[w][nl][m4] = pkv.ll;
            }
            // same-wave LDS round trip (lockstep; compiler inserts lgkmcnt)
            ushort_t* dst = bp + rbase0 + ((size_t)jt << 13) + (size_t)l * 16;
            union { unsigned long long q[2]; bf16x8 v; } s0, s1;
            s0.q[0] = lds_t[w][4 * (l & 3) + 0][m4d];
            s0.q[1] = lds_t[w][4 * (l & 3) + 1][m4d];
            s1.q[0] = lds_t[w][4 * (l & 3) + 2][m4d];
            s1.q[1] = lds_t[w][4 * (l & 3) + 3][m4d];
            *(bf16x8*)(dst) = s0.v;
            *(bf16x8*)(dst + 8) = s1.v;
        }
        return;
    }

    const int gid = bid - QKV_BIAS_BLKS;
    const int lane = t & 63, w = t >> 6;
    const int m16 = lane & 15, quad = lane >> 4;
    const int wr = w >> 1, wc = w & 1;
    const int r0 = (gid / 12) * 128, c0 = (gid % 12) * 128;

    const ushort_t* Ag = A  + (size_t)(r0 + (t >> 2)) * D_ + (t & 3) * 8;
    const ushort_t* Bg = Bt + (size_t)(c0 + (t >> 2)) * D_ + (t & 3) * 8;

    f32x4 acc[4][4];
    #pragma unroll
    for (int i = 0; i < 4; i++)
        #pragma unroll
        for (int j = 0; j < 4; j++) acc[i][j] = (f32x4){0.f, 0.f, 0.f, 0.f};

    // prologue: stage k0=0 into buf 0
    gl_lds16(Ag, As[0] + w * 512);
    gl_lds16(Ag + (size_t)64 * D_, As[0] + w * 512 + 2048);
    gl_lds16(Bg, Bs[0] + w * 512);
    gl_lds16(Bg + (size_t)64 * D_, Bs[0] + w * 512 + 2048);
    __syncthreads();

    for (int k0 = 0; k0 < D_; k0 += 32) {
        const int buf = (k0 >> 5) & 1;
        if (k0 + 32 < D_) {                  // issue next-step loads BEFORE compute
            gl_lds16(Ag + k0 + 32, As[buf ^ 1] + w * 512);
            gl_lds16(Ag + k0 + 32 + (size_t)64 * D_, As[buf ^ 1] + w * 512 + 2048);
            gl_lds16(Bg + k0 + 32, Bs[buf ^ 1] + w * 512);
            gl_lds16(Bg + k0 + 32 + (size_t)64 * D_, Bs[buf ^ 1] + w * 512 + 2048);
        }
        bf16x8 af[4], bfr[4];
        #pragma unroll
        for (int rt = 0; rt < 4; rt++)
            af[rt] = *(const bf16x8*)(As[buf] + (wr * 64 + rt * 16 + m16) * 32 + quad * 8);
        #pragma unroll
        for (int ct = 0; ct < 4; ct++)
            bfr[ct] = *(const bf16x8*)(Bs[buf] + (wc * 64 + ct * 16 + m16) * 32 + quad * 8);
        #pragma unroll
        for (int rt = 0; rt < 4; rt++)
            #pragma unroll
            for (int ct = 0; ct < 4; ct++)
                acc[rt][ct] = __builtin_amdgcn_mfma_f32_16x16x32_bf16(af[rt], bfr[ct], acc[rt][ct], 0, 0, 0);
        __syncthreads();                     // one barrier/step: drains loads into buf^1
    }

    const int b_blk = r0 >> 11, n_base = r0 & 2047;
    if ((c0 >> 9) == 2) {
        // ---- V epilogue: LDS restage, 256B-contiguous stores along n ----
        ushort_t* SH = As[0];                // 16KB contiguous
        #pragma unroll
        for (int ph = 0; ph < 2; ph++) {
            if (ph) __syncthreads();
            if (wc == ph) {
                #pragma unroll
                for (int ct = 0; ct < 4; ct++) {
                    int dcol = ct * 16 + m16;
                    #pragma unroll
                    for (int rt = 0; rt < 4; rt++) {
                        int nl = wr * 64 + rt * 16 + quad * 4;
                        union { ushort_t us[4]; unsigned long long ll; } pkv;
                        #pragma unroll
                        for (int r = 0; r < 4; r++) pkv.us[r] = f2bf(acc[rt][ct][r]);
                        *(unsigned long long*)(&SH[dcol * 128 + (nl ^ ((dcol & 7) << 3))]) = pkv.ll;
                    }
                }
            }
            __syncthreads();
            int h = ((c0 + ph * 64) >> 6) & 7;
            #pragma unroll
            for (int p = 0; p < 4; p++) {
                int dr = p * 16 + (t >> 4);
                int n0 = (t & 15) * 8;
                bf16x8 vv = *(const bf16x8*)&SH[dr * 128 + (n0 ^ ((dr & 7) << 3))];
                *(bf16x8*)(vb + ((size_t)(b_blk * H_ + h) * 64 + dr) * N_ + n_base + n0) = vv;
            }
        }
    } else {
        // ---- q/k epilogue (32B-run scalar stores) ----
        #pragma unroll
        for (int ct = 0; ct < 4; ct++) {
            int cc = c0 + wc * 64 + ct * 16;
            int which = cc >> 9;
            int h = (cc >> 6) & 7;
            int d = (cc & 63) + m16;
            #pragma unroll
            for (int rt = 0; rt < 4; rt++) {
                int rowb = r0 + wr * 64 + rt * 16 + quad * 4;
                int b = rowb >> 11, n0 = rowb & 2047;
                if (which == 0) {
                    #pragma unroll
                    for (int r = 0; r < 4; r++)
                        qb[((size_t)((b * H_ + h) * N_ + n0 + r)) * 64 + d] = f2bf(acc[rt][ct][r] * (0.125f * LOG2E));
                } else {
                    #pragma unroll
                    for (int r = 0; r < 4; r++)
                        kb[((size_t)((b * H_ + h) * N_ + n0 + r)) * 64 + d] = f2bf(acc[rt][ct][r]);
                }
            }
        }
    }
}

// ---------------- Out-proj v3: clean 2-phase pipelined K-loop ----------------
__global__ __launch_bounds__(256) void gemm_out(const ushort_t* __restrict__ A,
                                                const ushort_t* __restrict__ Bt,
                                                const float* __restrict__ bias,
                                                float* __restrict__ C) {
    __shared__ ushort_t As[2][2048];
    __shared__ ushort_t Bs[2][4096];
    const int t = threadIdx.x;
    const int lane = t & 63, w = t >> 6;
    const int m16 = lane & 15, quad = lane >> 4;
    const int wr = w >> 1, wc = w & 1;        // wave tile: 32 rows x 64 cols
    const int r0 = blockIdx.y * 64, c0 = blockIdx.x * 128;

    const ushort_t* Ag = A  + (size_t)(r0 + (t >> 2)) * D_ + (t & 3) * 8;
    const ushort_t* Bg = Bt + (size_t)(c0 + (t >> 2)) * D_ + (t & 3) * 8;

    f32x4 acc[2][4];
    #pragma unroll
    for (int i = 0; i < 2; i++)
        #pragma unroll
        for (int j = 0; j < 4; j++) acc[i][j] = (f32x4){0.f, 0.f, 0.f, 0.f};

    // prologue: stage k0=0 into buf 0 (A: 64r x 32k = 4KB; B: 128c x 32k = 8KB)
    gl_lds16(Ag, As[0] + w * 512);
    gl_lds16(Bg, Bs[0] + w * 512);
    gl_lds16(Bg + (size_t)64 * D_, Bs[0] + w * 512 + 2048);
    __syncthreads();

    for (int k0 = 0; k0 < D_; k0 += 32) {
        const int buf = (k0 >> 5) & 1;
        if (k0 + 32 < D_) {
            gl_lds16(Ag + k0 + 32, As[buf ^ 1] + w * 512);
            gl_lds16(Bg + k0 + 32, Bs[buf ^ 1] + w * 512);
            gl_lds16(Bg + k0 + 32 + (size_t)64 * D_, Bs[buf ^ 1] + w * 512 + 2048);
        }
        bf16x8 af[2], bfr[4];
        #pragma unroll
        for (int mf = 0; mf < 2; mf++)
            af[mf] = *(const bf16x8*)(As[buf] + (wr * 32 + mf * 16 + m16) * 32 + quad * 8);
        #pragma unroll
        for (int nt = 0; nt < 4; nt++)
            bfr[nt] = *(const bf16x8*)(Bs[buf] + (wc * 64 + nt * 16 + m16) * 32 + quad * 8);
        #pragma unroll
        for (int mf = 0; mf < 2; mf++)
            #pragma unroll
            for (int nt = 0; nt < 4; nt++)
                acc[mf][nt] = __builtin_amdgcn_mfma_f32_16x16x32_bf16(af[mf], bfr[nt], acc[mf][nt], 0, 0, 0);
        __syncthreads();
    }

    #pragma unroll
    for (int mf = 0; mf < 2; mf++) {
        #pragma unroll
        for (int nt = 0; nt < 4; nt++) {
            int col = c0 + wc * 64 + nt * 16 + m16;
            int row0 = r0 + wr * 32 + mf * 16 + quad * 4;
            float bv = bias[col];
            #pragma unroll
            for (int r = 0; r < 4; r++)
                C[(size_t)(row0 + r) * 512 + col] = acc[mf][nt][r] + bv;
        }
    }
}

// ---------------- MFMA flash attention v11: v10 + rsum via MFMA-with-ones ----------------
// rsum computed by 2 extra mfma(pa, ones): D[qrow][*] = rowsum lands exactly in the lane/row
// slots the normalizer needs (B=all-ones is layout-invariant). Deletes the 16-deep serial
// VALU add chain per tile and all end-of-kernel rsum shuffles.
#define ATTN_TILE(JT, KCUR, VCUR, KNXT, VNXT, BCUR, BNXT)                              \
  {                                                                                    \
    const int jt = (JT);                                                               \
    const int buf = jt & 1;                                                            \
    if (jt + 2 < 32) {                                                                 \
      KNXT = *(const bf16x8*)(kgbase + (size_t)((jt + 2) * 64 + srow) * 64 + scb * 8); \
      VNXT = *(const bf16x8*)(vgbase + (size_t)srow * N_ + (jt + 2) * 64 + scb * 8);   \
    }                                                                                  \
    if (jt + 1 < 32) {                                                                 \
      _Pragma("unroll")                                                                \
      for (int nt = 0; nt < 4; nt++)                                                   \
        BNXT[nt] = *(const bf16x4*)(bpb + ((jt + 1) << 13) + (nt << 8));               \
    }                                                                                  \
    unsigned pk[8];                                                                    \
    __builtin_amdgcn_s_setprio(1);                                                     \
    _Pragma("unroll")                                                                  \
    for (int nt = 0; nt < 4; nt++) {                                                   \
      f32x4 a2;                                                                        \
      _Pragma("unroll")                                                                \
      for (int r = 0; r < 4; r++) a2[r] = bf2f((ushort_t)BCUR[nt][r]);                 \
      int kr = nt * 16 + m16;                                                          \
      bf16x8 kf0 = *(const bf16x8*)(&Ks[buf][kr * 64 + ((quad) ^ (kr & 7)) * 8]);      \
      bf16x8 kf1 = *(const bf16x8*)(&Ks[buf][kr * 64 + ((quad + 4) ^ (kr & 7)) * 8]);  \
      a2 = __builtin_amdgcn_mfma_f32_16x16x32_bf16(kf0, qa0, a2, 0, 0, 0);             \
      a2 = __builtin_amdgcn_mfma_f32_16x16x32_bf16(kf1, qa1, a2, 0, 0, 0);             \
      float p0 = fexp2(a2[0]), p1 = fexp2(a2[1]);                                      \
      float p2 = fexp2(a2[2]), p3 = fexp2(a2[3]);                                      \
      pk[nt * 2]     = cvt_pk_bf16(p0, p1);                                            \
      pk[nt * 2 + 1] = cvt_pk_bf16(p2, p3);                                            \
    }                                                                                  \
    __builtin_amdgcn_s_setprio(0);                                                     \
    _Pragma("unroll")                                                                  \
    for (int i = 0; i < 4; i++) {                                                      \
      int chunk = 2 * i + (quad >> 1);                                                 \
      union { unsigned uu[2]; unsigned long long ll; } wrp;                            \
      wrp.uu[0] = pk[2 * i]; wrp.uu[1] = pk[2 * i + 1];                                \
      *(unsigned long long*)(pw + m16 * 64 + ((chunk ^ (m16 & 7)) << 3)                \
                             + (quad & 1) * 4) = wrp.ll;                               \
    }                                                                                  \
    bf16x8 pa0 = *(const bf16x8*)(pw + m16 * 64 + ((quad ^ (m16 & 7)) << 3));          \
    bf16x8 pa1 = *(const bf16x8*)(pw + m16 * 64 + (((quad + 4) ^ (m16 & 7)) << 3));    \
    __builtin_amdgcn_s_setprio(1);                                                     \
    rs = __builtin_amdgcn_mfma_f32_16x16x32_bf16(pa0, kones, rs, 0, 0, 0);             \
    rs = __builtin_amdgcn_mfma_f32_16x16x32_bf16(pa1, kones, rs, 0, 0, 0);             \
    _Pragma("unroll")                                                                  \
    for (int nt = 0; nt < 4; nt++) {                                                   \
      int d = nt * 16 + m16;                                                           \
      bf16x8 vf0 = *(const bf16x8*)(&Vs[buf][d * 64 + ((quad) ^ (d & 7)) * 8]);        \
      bf16x8 vf1 = *(const bf16x8*)(&Vs[buf][d * 64 + ((quad + 4) ^ (d & 7)) * 8]);    \
      o[nt] = __builtin_amdgcn_mfma_f32_16x16x32_bf16(pa0, vf0, o[nt], 0, 0, 0);       \
      o[nt] = __builtin_amdgcn_mfma_f32_16x16x32_bf16(pa1, vf1, o[nt], 0, 0, 0);       \
    }                                                                                  \
    __builtin_amdgcn_s_setprio(0);                                                     \
    if (jt + 1 < 32) {                                                                 \
      *(bf16x8*)(&Ks[buf ^ 1][soff]) = KCUR;                                           \
      *(bf16x8*)(&Vs[buf ^ 1][soff]) = VCUR;                                           \
    }                                                                                  \
    __syncthreads();                                                                   \
  }

__global__ __launch_bounds__(512, 4) void attn_mfma(const ushort_t* __restrict__ qb,
                                                    const ushort_t* __restrict__ kb,
                                                    const ushort_t* __restrict__ vb,
                                                    const ushort_t* __restrict__ bp,
                                                    ushort_t* __restrict__ attn) {
    __shared__ ushort_t Ks[2][64 * 64];      // [buf][key][d] swizzled, 8KB each
    __shared__ ushort_t Vs[2][64 * 64];      // [buf][d][key] swizzled, 8KB each
    __shared__ ushort_t p_s[8][16 * 64];     // [wave][qrow][key] swizzled, 16KB

    const int t = threadIdx.x;
    const int w = t >> 6, lane = t & 63;
    const int m16 = lane & 15, quad = lane >> 4;
    const int id = blockIdx.x;
    const int bh = id & 31;                  // XCD = id%8 = bh%8 (heuristic)
    const int qt = id >> 5;
    const int b = bh >> 3, h = bh & 7;
    const int n0w = qt * 128 + w * 16;

    // staging: thread stages exactly one 8-elem chunk of K and of V per tile
    const int srow = t >> 3, scb = t & 7;
    const int soff = srow * 64 + (scb ^ (srow & 7)) * 8;
    const ushort_t* kgbase = kb + ((size_t)bh * N_) * 64;   // [key][d]
    const ushort_t* vgbase = vb + ((size_t)bh * 64) * N_;   // [d][key]

    // Q frags (one 16-row m-frag per wave)
    const ushort_t* qpb = qb + ((size_t)(bh * N_ + n0w + m16)) * 64 + quad * 8;
    bf16x8 qa0 = *(const bf16x8*)(qpb);
    bf16x8 qa1 = *(const bf16x8*)(qpb + 32);

    // bias packed [qt][jt][w][nt][quad][m16][k4]; per phase the 16 m16-lanes read 128B contiguous
    const ushort_t* bpb = bp + ((size_t)qt << 18) + (w << 10) + (quad << 6) + (m16 << 2);

    // all-ones bf16 B-frag for the rowsum MFMA (layout-invariant)
    bf16x8 kones;
    #pragma unroll
    for (int i = 0; i < 8; i++) kones[i] = (short)0x3F80;

    // prologue: stage tile 0 into buf 0; prefetch tile 1 (regs) and bias jt=0 (regs)
    *(bf16x8*)(&Ks[0][soff]) = *(const bf16x8*)(kgbase + (size_t)srow * 64 + scb * 8);
    *(bf16x8*)(&Vs[0][soff]) = *(const bf16x8*)(vgbase + (size_t)srow * N_ + scb * 8);
    bf16x8 kA = *(const bf16x8*)(kgbase + (size_t)(64 + srow) * 64 + scb * 8);
    bf16x8 vA = *(const bf16x8*)(vgbase + (size_t)srow * N_ + 64 + scb * 8);
    bf16x8 kB, vB;
    bf16x4 bA[4], bB[4];
    #pragma unroll
    for (int nt = 0; nt < 4; nt++) bA[nt] = *(const bf16x4*)(bpb + (nt << 8));
    __syncthreads();

    f32x4 o[4];
    #pragma unroll
    for (int nt = 0; nt < 4; nt++) o[nt] = (f32x4){0.f, 0.f, 0.f, 0.f};
    f32x4 rs = (f32x4){0.f, 0.f, 0.f, 0.f};

    ushort_t* pw = p_s[w];

    for (int jt2 = 0; jt2 < 16; jt2++) {
        ATTN_TILE(2 * jt2,     kA, vA, kB, vB, bA, bB);
        ATTN_TILE(2 * jt2 + 1, kB, vB, kA, vA, bB, bA);
    }

    // ---- normalize + store: o[nt][r] is (qrow=quad*4+r, d=nt*16+m16); rs[r] = rowsum(qrow) ----
    #pragma unroll
    for (int r = 0; r < 4; r++) {
        float inv = 1.0f / rs[r];
        int n = n0w + quad * 4 + r;
        ushort_t* orow = attn + ((size_t)(b * N_ + n)) * 512 + h * 64 + m16;
        #pragma unroll
        for (int nt = 0; nt < 4; nt++) orow[nt * 16] = f2bf(o[nt][r] * inv);
    }
}

extern "C" void kernel_launch(void* const* d_in, const int* in_sizes, int n_in,
                              void* d_out, int out_size, void* d_ws, size_t ws_size,
                              hipStream_t stream) {
    const float* x     = (const float*)d_in[0];
    const float* gamma = (const float*)d_in[1];
    const float* beta  = (const float*)d_in[2];
    const float* Wqkv  = (const float*)d_in[3];
    const float* Wout  = (const float*)d_in[4];
    const float* bout  = (const float*)d_in[5];
    const float* rel   = (const float*)d_in[6];
    const int*   mask  = (const int*)d_in[7];
    float* out = (float*)d_out;

    char* wsb = (char*)d_ws;
    ushort_t* xn    = (ushort_t*)(wsb);                    //  8 MB
    ushort_t* attnb = (ushort_t*)(wsb + ( 8u << 20));      //  8 MB
    ushort_t* qb    = (ushort_t*)(wsb + (16u << 20));      //  8 MB
    ushort_t* kb    = (ushort_t*)(wsb + (24u << 20));      //  8 MB
    ushort_t* vb    = (ushort_t*)(wsb + (32u << 20));      //  8 MB
    ushort_t* WqkvT = (ushort_t*)(wsb + (40u << 20));      //  1.5 MB
    ushort_t* WoutT = (ushort_t*)(wsb + (42u << 20));      //  0.5 MB
    ushort_t* bp    = (ushort_t*)(wsb + (44u << 20));      //  8 MB

    // 1. prep: layernorm + both weight transposes
    prep_kernel<<<PREP_LN + PREP_WQ + PREP_WO, 256, 0, stream>>>(
        x, gamma, beta, xn, Wqkv, WqkvT, Wout, WoutT);

    // 2. QKV projection (pipelined MFMA + global_load_lds) + concurrent bias-pack blocks
    gemm_qkv<<<QKV_BIAS_BLKS + 768, 256, 0, stream>>>(xn, WqkvT, qb, kb, vb, rel, mask, bp);

    // 3. MFMA flash attention v11 -> bf16
    attn_mfma<<<512, 512, 0, stream>>>(qb, kb, vb, bp, attnb);

    // 4. output projection + bias (pipelined MFMA + global_load_lds) -> fp32
    gemm_out<<<dim3(512 / 128, 8192 / 64), 256, 0, stream>>>(attnb, WoutT, bout, out);
}

// Round 11
// 192.991 us; speedup vs baseline: 1.0152x; 1.0119x over previous
//
#include <hip/hip_runtime.h>

typedef __attribute__((ext_vector_type(8))) short bf16x8;
typedef __attribute__((ext_vector_type(4))) short bf16x4;
typedef __attribute__((ext_vector_type(4))) float f32x4;
typedef unsigned short ushort_t;

#define B_ 4
#define H_ 8
#define N_ 2048
#define D_ 512
#define MAXREL 199   // MAX_REL-1
#define LOG2E 1.4426950408889634f

__device__ __forceinline__ ushort_t f2bf(float f) {
    union { float f; unsigned u; } v; v.f = f;
    unsigned r = v.u + 0x7fffu + ((v.u >> 16) & 1u);
    return (ushort_t)(r >> 16);
}
__device__ __forceinline__ float bf2f(ushort_t u) {
    union { unsigned u; float f; } v; v.u = ((unsigned)u) << 16;
    return v.f;
}
__device__ __forceinline__ float fexp2(float x) {
#if __has_builtin(__builtin_amdgcn_exp2f)
    return __builtin_amdgcn_exp2f(x);
#else
    return __expf(x * 0.6931471805599453f);
#endif
}
__device__ __forceinline__ unsigned cvt_pk_bf16(float lo, float hi) {
    unsigned r;
    asm("v_cvt_pk_bf16_f32 %0, %1, %2" : "=v"(r) : "v"(lo), "v"(hi));
    return r;
}
// async global->LDS, 16B per lane; lds dest = wave-uniform base + lane*16
__device__ __forceinline__ void gl_lds16(const ushort_t* g, ushort_t* l) {
    __builtin_amdgcn_global_load_lds(
        (const __attribute__((address_space(1))) void*)g,
        (__attribute__((address_space(3))) void*)l,
        16, 0, 0);
}

// ---------------- prep v3: layernorm (wave-per-row) | wtrans(Wqkv) | wtrans(Wout) ----------------
#define PREP_LN    2048                     // (B*N)/4 rows
#define PREP_WQ    768                      // (1536/32)*(512/32)
#define PREP_WO    256                      // (512/32)*(512/32)
__global__ __launch_bounds__(256) void prep_kernel(const float* __restrict__ x,
                                                   const float* __restrict__ gamma,
                                                   const float* __restrict__ beta,
                                                   ushort_t* __restrict__ xn,
                                                   const float* __restrict__ Wqkv,
                                                   ushort_t* __restrict__ WqkvT,
                                                   const float* __restrict__ Wout,
                                                   ushort_t* __restrict__ WoutT) {
    __shared__ float smem[32 * 33];
    const int blk = blockIdx.x;
    const int t = threadIdx.x;

    if (blk < PREP_LN) {
        // ---- LayerNorm: one 64-lane wave per row, float4 loads, butterfly reduce (verified r6) ----
        const int row = blk * 4 + (t >> 6);
        const int l = t & 63;
        const float* xr = x + (size_t)row * D_;
        float4 a = *(const float4*)&xr[l * 4];
        float4 c = *(const float4*)&xr[256 + l * 4];
        float s = (a.x + a.y) + (a.z + a.w) + (c.x + c.y) + (c.z + c.w);
        #pragma unroll
        for (int o = 1; o < 64; o <<= 1) s += __shfl_xor(s, o);
        float mu = s * (1.0f / D_);
        float dx0 = a.x - mu, dx1 = a.y - mu, dx2 = a.z - mu, dx3 = a.w - mu;
        float dy0 = c.x - mu, dy1 = c.y - mu, dy2 = c.z - mu, dy3 = c.w - mu;
        float s2 = dx0*dx0 + dx1*dx1 + dx2*dx2 + dx3*dx3
                 + dy0*dy0 + dy1*dy1 + dy2*dy2 + dy3*dy3;
        #pragma unroll
        for (int o = 1; o < 64; o <<= 1) s2 += __shfl_xor(s2, o);
        float rs = rsqrtf(s2 * (1.0f / D_) + 1e-5f);
        float4 g1 = *(const float4*)&gamma[l * 4];
        float4 g2 = *(const float4*)&gamma[256 + l * 4];
        float4 b1 = *(const float4*)&beta[l * 4];
        float4 b2 = *(const float4*)&beta[256 + l * 4];
        ushort_t* yr = xn + (size_t)row * D_;
        union { ushort_t us[4]; unsigned long long ll; } o1, o2;
        o1.us[0] = f2bf(dx0 * rs * g1.x + b1.x);
        o1.us[1] = f2bf(dx1 * rs * g1.y + b1.y);
        o1.us[2] = f2bf(dx2 * rs * g1.z + b1.z);
        o1.us[3] = f2bf(dx3 * rs * g1.w + b1.w);
        o2.us[0] = f2bf(dy0 * rs * g2.x + b2.x);
        o2.us[1] = f2bf(dy1 * rs * g2.y + b2.y);
        o2.us[2] = f2bf(dy2 * rs * g2.z + b2.z);
        o2.us[3] = f2bf(dy3 * rs * g2.w + b2.w);
        *(unsigned long long*)(yr + l * 4) = o1.ll;
        *(unsigned long long*)(yr + 256 + l * 4) = o2.ll;
    } else {
        // ---- weight transpose fp32 [K][Nn] -> bf16 [Nn][K] ----
        const float* W; ushort_t* Wt; int Nn, i;
        if (blk < PREP_LN + PREP_WQ) {
            i = blk - PREP_LN; W = Wqkv; Wt = WqkvT; Nn = 1536;
        } else {
            i = blk - (PREP_LN + PREP_WQ); W = Wout; Wt = WoutT; Nn = 512;
        }
        const int nb = Nn >> 5;
        const int bx = (i % nb) * 32, by = (i / nb) * 32;
        const int tx = t & 31, ty = t >> 5;
        float (*tile)[33] = (float(*)[33])smem;
        #pragma unroll
        for (int k = 0; k < 32; k += 8)
            tile[ty + k][tx] = W[(size_t)(by + ty + k) * Nn + bx + tx];
        __syncthreads();
        #pragma unroll
        for (int k = 0; k < 32; k += 8)
            Wt[(size_t)(bx + ty + k) * 512 + by + tx] = f2bf(tile[tx][ty + k]);
    }
}

// ---------------- QKV GEMM v6: pipelined K-loop + r8 bias-pack + XCD-swizzled tiles ----------------
// Bias-pack: r8-verified 512-block version (co-measured gemm_qkv 56-58us).
// GEMM tiles XCD-swizzled (T1): 768 = 8 XCDs x 96 tiles; each XCD owns 8 contiguous
// 128-row A-panels (1MB, L2-resident) instead of striping panels across all XCDs.
#define QKV_BIAS_BLKS 512
__global__ __launch_bounds__(256) void gemm_qkv(const ushort_t* __restrict__ A,
                                                const ushort_t* __restrict__ Bt,
                                                ushort_t* __restrict__ qb,
                                                ushort_t* __restrict__ kb,
                                                ushort_t* __restrict__ vb,
                                                const float* __restrict__ rel,
                                                const int* __restrict__ mask,
                                                ushort_t* __restrict__ bp) {
    const int bid = blockIdx.x;
    const int t = threadIdx.x;

    if (bid < QKV_BIAS_BLKS) {
        // ---- bias+mask pack into [qt][jt][w][nt][quad][m16][k4] order, log2 domain (r8) ----
        const int base = bid * 8192;
        #pragma unroll
        for (int p = 0; p < 8; p++) {
            int idx = base + p * 1024 + t * 4;   // 4 consecutive m, same n
            int n = idx >> 11, m = idx & 2047;
            const int4 mv = *(const int4*)&mask[idx];
            union { ushort_t us[4]; unsigned long long ll; } pkv;
            #pragma unroll
            for (int j = 0; j < 4; j++) {
                int dl = n - (m + j);
                dl = dl < -MAXREL ? -MAXREL : (dl > MAXREL ? MAXREL : dl);
                int mj = (j == 0) ? mv.x : (j == 1) ? mv.y : (j == 2) ? mv.z : mv.w;
                float v = (mj == 0) ? -1e9f : rel[dl + MAXREL] * LOG2E;
                pkv.us[j] = f2bf(v);
            }
            int off = ((n >> 7) << 18) + ((m >> 6) << 13) + (((n >> 4) & 7) << 10)
                    + (((m >> 4) & 3) << 8) + (((m >> 2) & 3) << 6) + ((n & 15) << 2);
            *(unsigned long long*)(bp + off) = pkv.ll;
        }
        return;
    }

    __shared__ ushort_t As[2][4096];         // 16KB (also reused as v-restage buffer)
    __shared__ ushort_t Bs[2][4096];         // 16KB
    const int g = bid - QKV_BIAS_BLKS;       // 0..767
    // XCD swizzle: XCD(bid) = bid%8 (heuristic); give each XCD 96 contiguous tiles
    const int tid = (g & 7) * 96 + (g >> 3);
    const int lane = t & 63, w = t >> 6;
    const int m16 = lane & 15, quad = lane >> 4;
    const int wr = w >> 1, wc = w & 1;
    const int r0 = (tid / 12) * 128, c0 = (tid % 12) * 128;

    const ushort_t* Ag = A  + (size_t)(r0 + (t >> 2)) * D_ + (t & 3) * 8;
    const ushort_t* Bg = Bt + (size_t)(c0 + (t >> 2)) * D_ + (t & 3) * 8;

    f32x4 acc[4][4];
    #pragma unroll
    for (int i = 0; i < 4; i++)
        #pragma unroll
        for (int j = 0; j < 4; j++) acc[i][j] = (f32x4){0.f, 0.f, 0.f, 0.f};

    // prologue: stage k0=0 into buf 0
    gl_lds16(Ag, As[0] + w * 512);
    gl_lds16(Ag + (size_t)64 * D_, As[0] + w * 512 + 2048);
    gl_lds16(Bg, Bs[0] + w * 512);
    gl_lds16(Bg + (size_t)64 * D_, Bs[0] + w * 512 + 2048);
    __syncthreads();

    for (int k0 = 0; k0 < D_; k0 += 32) {
        const int buf = (k0 >> 5) & 1;
        if (k0 + 32 < D_) {                  // issue next-step loads BEFORE compute
            gl_lds16(Ag + k0 + 32, As[buf ^ 1] + w * 512);
            gl_lds16(Ag + k0 + 32 + (size_t)64 * D_, As[buf ^ 1] + w * 512 + 2048);
            gl_lds16(Bg + k0 + 32, Bs[buf ^ 1] + w * 512);
            gl_lds16(Bg + k0 + 32 + (size_t)64 * D_, Bs[buf ^ 1] + w * 512 + 2048);
        }
        bf16x8 af[4], bfr[4];
        #pragma unroll
        for (int rt = 0; rt < 4; rt++)
            af[rt] = *(const bf16x8*)(As[buf] + (wr * 64 + rt * 16 + m16) * 32 + quad * 8);
        #pragma unroll
        for (int ct = 0; ct < 4; ct++)
            bfr[ct] = *(const bf16x8*)(Bs[buf] + (wc * 64 + ct * 16 + m16) * 32 + quad * 8);
        #pragma unroll
        for (int rt = 0; rt < 4; rt++)
            #pragma unroll
            for (int ct = 0; ct < 4; ct++)
                acc[rt][ct] = __builtin_amdgcn_mfma_f32_16x16x32_bf16(af[rt], bfr[ct], acc[rt][ct], 0, 0, 0);
        __syncthreads();                     // one barrier/step: drains loads into buf^1
    }

    const int b_blk = r0 >> 11, n_base = r0 & 2047;
    if ((c0 >> 9) == 2) {
        // ---- V epilogue: LDS restage, 256B-contiguous stores along n ----
        ushort_t* SH = As[0];                // 16KB contiguous
        #pragma unroll
        for (int ph = 0; ph < 2; ph++) {
            if (ph) __syncthreads();
            if (wc == ph) {
                #pragma unroll
                for (int ct = 0; ct < 4; ct++) {
                    int dcol = ct * 16 + m16;
                    #pragma unroll
                    for (int rt = 0; rt < 4; rt++) {
                        int nl = wr * 64 + rt * 16 + quad * 4;
                        union { ushort_t us[4]; unsigned long long ll; } pkv;
                        #pragma unroll
                        for (int r = 0; r < 4; r++) pkv.us[r] = f2bf(acc[rt][ct][r]);
                        *(unsigned long long*)(&SH[dcol * 128 + (nl ^ ((dcol & 7) << 3))]) = pkv.ll;
                    }
                }
            }
            __syncthreads();
            int h = ((c0 + ph * 64) >> 6) & 7;
            #pragma unroll
            for (int p = 0; p < 4; p++) {
                int dr = p * 16 + (t >> 4);
                int n0 = (t & 15) * 8;
                bf16x8 vv = *(const bf16x8*)&SH[dr * 128 + (n0 ^ ((dr & 7) << 3))];
                *(bf16x8*)(vb + ((size_t)(b_blk * H_ + h) * 64 + dr) * N_ + n_base + n0) = vv;
            }
        }
    } else {
        // ---- q/k epilogue (32B-run scalar stores) ----
        #pragma unroll
        for (int ct = 0; ct < 4; ct++) {
            int cc = c0 + wc * 64 + ct * 16;
            int which = cc >> 9;
            int h = (cc >> 6) & 7;
            int d = (cc & 63) + m16;
            #pragma unroll
            for (int rt = 0; rt < 4; rt++) {
                int rowb = r0 + wr * 64 + rt * 16 + quad * 4;
                int b = rowb >> 11, n0 = rowb & 2047;
                if (which == 0) {
                    #pragma unroll
                    for (int r = 0; r < 4; r++)
                        qb[((size_t)((b * H_ + h) * N_ + n0 + r)) * 64 + d] = f2bf(acc[rt][ct][r] * (0.125f * LOG2E));
                } else {
                    #pragma unroll
                    for (int r = 0; r < 4; r++)
                        kb[((size_t)((b * H_ + h) * N_ + n0 + r)) * 64 + d] = f2bf(acc[rt][ct][r]);
                }
            }
        }
    }
}

// ---------------- Out-proj v4: pipelined K-loop + XCD-swizzled 1-D grid ----------------
__global__ __launch_bounds__(256) void gemm_out(const ushort_t* __restrict__ A,
                                                const ushort_t* __restrict__ Bt,
                                                const float* __restrict__ bias,
                                                float* __restrict__ C) {
    __shared__ ushort_t As[2][2048];
    __shared__ ushort_t Bs[2][4096];
    const int t = threadIdx.x;
    const int lane = t & 63, w = t >> 6;
    const int m16 = lane & 15, quad = lane >> 4;
    const int wr = w >> 1, wc = w & 1;        // wave tile: 32 rows x 64 cols
    // XCD swizzle: 512 = 8 XCDs x 64 tiles; each XCD owns 16 contiguous 64-row A-panels
    const int bswz = (blockIdx.x & 7) * 64 + (blockIdx.x >> 3);
    const int r0 = (bswz >> 2) * 64, c0 = (bswz & 3) * 128;

    const ushort_t* Ag = A  + (size_t)(r0 + (t >> 2)) * D_ + (t & 3) * 8;
    const ushort_t* Bg = Bt + (size_t)(c0 + (t >> 2)) * D_ + (t & 3) * 8;

    f32x4 acc[2][4];
    #pragma unroll
    for (int i = 0; i < 2; i++)
        #pragma unroll
        for (int j = 0; j < 4; j++) acc[i][j] = (f32x4){0.f, 0.f, 0.f, 0.f};

    // prologue: stage k0=0 into buf 0 (A: 64r x 32k = 4KB; B: 128c x 32k = 8KB)
    gl_lds16(Ag, As[0] + w * 512);
    gl_lds16(Bg, Bs[0] + w * 512);
    gl_lds16(Bg + (size_t)64 * D_, Bs[0] + w * 512 + 2048);
    __syncthreads();

    for (int k0 = 0; k0 < D_; k0 += 32) {
        const int buf = (k0 >> 5) & 1;
        if (k0 + 32 < D_) {
            gl_lds16(Ag + k0 + 32, As[buf ^ 1] + w * 512);
            gl_lds16(Bg + k0 + 32, Bs[buf ^ 1] + w * 512);
            gl_lds16(Bg + k0 + 32 + (size_t)64 * D_, Bs[buf ^ 1] + w * 512 + 2048);
        }
        bf16x8 af[2], bfr[4];
        #pragma unroll
        for (int mf = 0; mf < 2; mf++)
            af[mf] = *(const bf16x8*)(As[buf] + (wr * 32 + mf * 16 + m16) * 32 + quad * 8);
        #pragma unroll
        for (int nt = 0; nt < 4; nt++)
            bfr[nt] = *(const bf16x8*)(Bs[buf] + (wc * 64 + nt * 16 + m16) * 32 + quad * 8);
        #pragma unroll
        for (int mf = 0; mf < 2; mf++)
            #pragma unroll
            for (int nt = 0; nt < 4; nt++)
                acc[mf][nt] = __builtin_amdgcn_mfma_f32_16x16x32_bf16(af[mf], bfr[nt], acc[mf][nt], 0, 0, 0);
        __syncthreads();
    }

    #pragma unroll
    for (int mf = 0; mf < 2; mf++) {
        #pragma unroll
        for (int nt = 0; nt < 4; nt++) {
            int col = c0 + wc * 64 + nt * 16 + m16;
            int row0 = r0 + wr * 32 + mf * 16 + quad * 4;
            float bv = bias[col];
            #pragma unroll
            for (int r = 0; r < 4; r++)
                C[(size_t)(row0 + r) * 512 + col] = acc[mf][nt][r] + bv;
        }
    }
}

// ---------------- MFMA flash attention v11 (r9-verified): rsum via MFMA-with-ones ----------------
#define ATTN_TILE(JT, KCUR, VCUR, KNXT, VNXT, BCUR, BNXT)                              \
  {                                                                                    \
    const int jt = (JT);                                                               \
    const int buf = jt & 1;                                                            \
    if (jt + 2 < 32) {                                                                 \
      KNXT = *(const bf16x8*)(kgbase + (size_t)((jt + 2) * 64 + srow) * 64 + scb * 8); \
      VNXT = *(const bf16x8*)(vgbase + (size_t)srow * N_ + (jt + 2) * 64 + scb * 8);   \
    }                                                                                  \
    if (jt + 1 < 32) {                                                                 \
      _Pragma("unroll")                                                                \
      for (int nt = 0; nt < 4; nt++)                                                   \
        BNXT[nt] = *(const bf16x4*)(bpb + ((jt + 1) << 13) + (nt << 8));               \
    }                                                                                  \
    unsigned pk[8];                                                                    \
    __builtin_amdgcn_s_setprio(1);                                                     \
    _Pragma("unroll")                                                                  \
    for (int nt = 0; nt < 4; nt++) {                                                   \
      f32x4 a2;                                                                        \
      _Pragma("unroll")                                                                \
      for (int r = 0; r < 4; r++) a2[r] = bf2f((ushort_t)BCUR[nt][r]);                 \
      int kr = nt * 16 + m16;                                                          \
      bf16x8 kf0 = *(const bf16x8*)(&Ks[buf][kr * 64 + ((quad) ^ (kr & 7)) * 8]);      \
      bf16x8 kf1 = *(const bf16x8*)(&Ks[buf][kr * 64 + ((quad + 4) ^ (kr & 7)) * 8]);  \
      a2 = __builtin_amdgcn_mfma_f32_16x16x32_bf16(kf0, qa0, a2, 0, 0, 0);             \
      a2 = __builtin_amdgcn_mfma_f32_16x16x32_bf16(kf1, qa1, a2, 0, 0, 0);             \
      float p0 = fexp2(a2[0]), p1 = fexp2(a2[1]);                                      \
      float p2 = fexp2(a2[2]), p3 = fexp2(a2[3]);                                      \
      pk[nt * 2]     = cvt_pk_bf16(p0, p1);                                            \
      pk[nt * 2 + 1] = cvt_pk_bf16(p2, p3);                                            \
    }                                                                                  \
    __builtin_amdgcn_s_setprio(0);                                                     \
    _Pragma("unroll")                                                                  \
    for (int i = 0; i < 4; i++) {                                                      \
      int chunk = 2 * i + (quad >> 1);                                                 \
      union { unsigned uu[2]; unsigned long long ll; } wrp;                            \
      wrp.uu[0] = pk[2 * i]; wrp.uu[1] = pk[2 * i + 1];                                \
      *(unsigned long long*)(pw + m16 * 64 + ((chunk ^ (m16 & 7)) << 3)                \
                             + (quad & 1) * 4) = wrp.ll;                               \
    }                                                                                  \
    bf16x8 pa0 = *(const bf16x8*)(pw + m16 * 64 + ((quad ^ (m16 & 7)) << 3));          \
    bf16x8 pa1 = *(const bf16x8*)(pw + m16 * 64 + (((quad + 4) ^ (m16 & 7)) << 3));    \
    __builtin_amdgcn_s_setprio(1);                                                     \
    rs = __builtin_amdgcn_mfma_f32_16x16x32_bf16(pa0, kones, rs, 0, 0, 0);             \
    rs = __builtin_amdgcn_mfma_f32_16x16x32_bf16(pa1, kones, rs, 0, 0, 0);             \
    _Pragma("unroll")                                                                  \
    for (int nt = 0; nt < 4; nt++) {                                                   \
      int d = nt * 16 + m16;                                                           \
      bf16x8 vf0 = *(const bf16x8*)(&Vs[buf][d * 64 + ((quad) ^ (d & 7)) * 8]);        \
      bf16x8 vf1 = *(const bf16x8*)(&Vs[buf][d * 64 + ((quad + 4) ^ (d & 7)) * 8]);    \
      o[nt] = __builtin_amdgcn_mfma_f32_16x16x32_bf16(pa0, vf0, o[nt], 0, 0, 0);       \
      o[nt] = __builtin_amdgcn_mfma_f32_16x16x32_bf16(pa1, vf1, o[nt], 0, 0, 0);       \
    }                                                                                  \
    __builtin_amdgcn_s_setprio(0);                                                     \
    if (jt + 1 < 32) {                                                                 \
      *(bf16x8*)(&Ks[buf ^ 1][soff]) = KCUR;                                           \
      *(bf16x8*)(&Vs[buf ^ 1][soff]) = VCUR;                                           \
    }                                                                                  \
    __syncthreads();                                                                   \
  }

__global__ __launch_bounds__(512, 4) void attn_mfma(const ushort_t* __restrict__ qb,
                                                    const ushort_t* __restrict__ kb,
                                                    const ushort_t* __restrict__ vb,
                                                    const ushort_t* __restrict__ bp,
                                                    ushort_t* __restrict__ attn) {
    __shared__ ushort_t Ks[2][64 * 64];      // [buf][key][d] swizzled, 8KB each
    __shared__ ushort_t Vs[2][64 * 64];      // [buf][d][key] swizzled, 8KB each
    __shared__ ushort_t p_s[8][16 * 64];     // [wave][qrow][key] swizzled, 16KB

    const int t = threadIdx.x;
    const int w = t >> 6, lane = t & 63;
    const int m16 = lane & 15, quad = lane >> 4;
    const int id = blockIdx.x;
    const int bh = id & 31;                  // XCD = id%8 = bh%8 (heuristic)
    const int qt = id >> 5;
    const int b = bh >> 3, h = bh & 7;
    const int n0w = qt * 128 + w * 16;

    // staging: thread stages exactly one 8-elem chunk of K and of V per tile
    const int srow = t >> 3, scb = t & 7;
    const int soff = srow * 64 + (scb ^ (srow & 7)) * 8;
    const ushort_t* kgbase = kb + ((size_t)bh * N_) * 64;   // [key][d]
    const ushort_t* vgbase = vb + ((size_t)bh * 64) * N_;   // [d][key]

    // Q frags (one 16-row m-frag per wave)
    const ushort_t* qpb = qb + ((size_t)(bh * N_ + n0w + m16)) * 64 + quad * 8;
    bf16x8 qa0 = *(const bf16x8*)(qpb);
    bf16x8 qa1 = *(const bf16x8*)(qpb + 32);

    // bias packed [qt][jt][w][nt][quad][m16][k4]; per phase the 16 m16-lanes read 128B contiguous
    const ushort_t* bpb = bp + ((size_t)qt << 18) + (w << 10) + (quad << 6) + (m16 << 2);

    // all-ones bf16 B-frag for the rowsum MFMA (layout-invariant)
    bf16x8 kones;
    #pragma unroll
    for (int i = 0; i < 8; i++) kones[i] = (short)0x3F80;

    // prologue: stage tile 0 into buf 0; prefetch tile 1 (regs) and bias jt=0 (regs)
    *(bf16x8*)(&Ks[0][soff]) = *(const bf16x8*)(kgbase + (size_t)srow * 64 + scb * 8);
    *(bf16x8*)(&Vs[0][soff]) = *(const bf16x8*)(vgbase + (size_t)srow * N_ + scb * 8);
    bf16x8 kA = *(const bf16x8*)(kgbase + (size_t)(64 + srow) * 64 + scb * 8);
    bf16x8 vA = *(const bf16x8*)(vgbase + (size_t)srow * N_ + 64 + scb * 8);
    bf16x8 kB, vB;
    bf16x4 bA[4], bB[4];
    #pragma unroll
    for (int nt = 0; nt < 4; nt++) bA[nt] = *(const bf16x4*)(bpb + (nt << 8));
    __syncthreads();

    f32x4 o[4];
    #pragma unroll
    for (int nt = 0; nt < 4; nt++) o[nt] = (f32x4){0.f, 0.f, 0.f, 0.f};
    f32x4 rs = (f32x4){0.f, 0.f, 0.f, 0.f};

    ushort_t* pw = p_s[w];

    for (int jt2 = 0; jt2 < 16; jt2++) {
        ATTN_TILE(2 * jt2,     kA, vA, kB, vB, bA, bB);
        ATTN_TILE(2 * jt2 + 1, kB, vB, kA, vA, bB, bA);
    }

    // ---- normalize + store: o[nt][r] is (qrow=quad*4+r, d=nt*16+m16); rs[r] = rowsum(qrow) ----
    #pragma unroll
    for (int r = 0; r < 4; r++) {
        float inv = 1.0f / rs[r];
        int n = n0w + quad * 4 + r;
        ushort_t* orow = attn + ((size_t)(b * N_ + n)) * 512 + h * 64 + m16;
        #pragma unroll
        for (int nt = 0; nt < 4; nt++) orow[nt * 16] = f2bf(o[nt][r] * inv);
    }
}

extern "C" void kernel_launch(void* const* d_in, const int* in_sizes, int n_in,
                              void* d_out, int out_size, void* d_ws, size_t ws_size,
                              hipStream_t stream) {
    const float* x     = (const float*)d_in[0];
    const float* gamma = (const float*)d_in[1];
    const float* beta  = (const float*)d_in[2];
    const float* Wqkv  = (const float*)d_in[3];
    const float* Wout  = (const float*)d_in[4];
    const float* bout  = (const float*)d_in[5];
    const float* rel   = (const float*)d_in[6];
    const int*   mask  = (const int*)d_in[7];
    float* out = (float*)d_out;

    char* wsb = (char*)d_ws;
    ushort_t* xn    = (ushort_t*)(wsb);                    //  8 MB
    ushort_t* attnb = (ushort_t*)(wsb + ( 8u << 20));      //  8 MB
    ushort_t* qb    = (ushort_t*)(wsb + (16u << 20));      //  8 MB
    ushort_t* kb    = (ushort_t*)(wsb + (24u << 20));      //  8 MB
    ushort_t* vb    = (ushort_t*)(wsb + (32u << 20));      //  8 MB
    ushort_t* WqkvT = (ushort_t*)(wsb + (40u << 20));      //  1.5 MB
    ushort_t* WoutT = (ushort_t*)(wsb + (42u << 20));      //  0.5 MB
    ushort_t* bp    = (ushort_t*)(wsb + (44u << 20));      //  8 MB

    // 1. prep: layernorm + both weight transposes
    prep_kernel<<<PREP_LN + PREP_WQ + PREP_WO, 256, 0, stream>>>(
        x, gamma, beta, xn, Wqkv, WqkvT, Wout, WoutT);

    // 2. QKV projection (pipelined MFMA, XCD-swizzled) + concurrent bias-pack blocks
    gemm_qkv<<<QKV_BIAS_BLKS + 768, 256, 0, stream>>>(xn, WqkvT, qb, kb, vb, rel, mask, bp);

    // 3. MFMA flash attention v11 -> bf16
    attn_mfma<<<512, 512, 0, stream>>>(qb, kb, vb, bp, attnb);

    // 4. output projection + bias (pipelined MFMA, XCD-swizzled) -> fp32
    gemm_out<<<512, 256, 0, stream>>>(attnb, WoutT, bout, out);
}

// Round 12
// 186.856 us; speedup vs baseline: 1.0485x; 1.0328x over previous
//
#include <hip/hip_runtime.h>

typedef __attribute__((ext_vector_type(8))) short bf16x8;
typedef __attribute__((ext_vector_type(4))) short bf16x4;
typedef __attribute__((ext_vector_type(4))) float f32x4;
typedef unsigned short ushort_t;

#define B_ 4
#define H_ 8
#define N_ 2048
#define D_ 512
#define MAXREL 199   // MAX_REL-1
#define LOG2E 1.4426950408889634f

__device__ __forceinline__ ushort_t f2bf(float f) {
    union { float f; unsigned u; } v; v.f = f;
    unsigned r = v.u + 0x7fffu + ((v.u >> 16) & 1u);
    return (ushort_t)(r >> 16);
}
__device__ __forceinline__ float bf2f(ushort_t u) {
    union { unsigned u; float f; } v; v.u = ((unsigned)u) << 16;
    return v.f;
}
__device__ __forceinline__ float fexp2(float x) {
#if __has_builtin(__builtin_amdgcn_exp2f)
    return __builtin_amdgcn_exp2f(x);
#else
    return __expf(x * 0.6931471805599453f);
#endif
}
__device__ __forceinline__ unsigned cvt_pk_bf16(float lo, float hi) {
    unsigned r;
    asm("v_cvt_pk_bf16_f32 %0, %1, %2" : "=v"(r) : "v"(lo), "v"(hi));
    return r;
}
// async global->LDS, 16B per lane; lds dest = wave-uniform base + lane*16
__device__ __forceinline__ void gl_lds16(const ushort_t* g, ushort_t* l) {
    __builtin_amdgcn_global_load_lds(
        (const __attribute__((address_space(1))) void*)g,
        (__attribute__((address_space(3))) void*)l,
        16, 0, 0);
}

// ---------------- prep v3: layernorm (wave-per-row) | wtrans(Wqkv) | wtrans(Wout) ----------------
#define PREP_LN    2048                     // (B*N)/4 rows
#define PREP_WQ    768                      // (1536/32)*(512/32)
#define PREP_WO    256                      // (512/32)*(512/32)
__global__ __launch_bounds__(256) void prep_kernel(const float* __restrict__ x,
                                                   const float* __restrict__ gamma,
                                                   const float* __restrict__ beta,
                                                   ushort_t* __restrict__ xn,
                                                   const float* __restrict__ Wqkv,
                                                   ushort_t* __restrict__ WqkvT,
                                                   const float* __restrict__ Wout,
                                                   ushort_t* __restrict__ WoutT) {
    __shared__ float smem[32 * 33];
    const int blk = blockIdx.x;
    const int t = threadIdx.x;

    if (blk < PREP_LN) {
        // ---- LayerNorm: one 64-lane wave per row, float4 loads, butterfly reduce (verified r6) ----
        const int row = blk * 4 + (t >> 6);
        const int l = t & 63;
        const float* xr = x + (size_t)row * D_;
        float4 a = *(const float4*)&xr[l * 4];
        float4 c = *(const float4*)&xr[256 + l * 4];
        float s = (a.x + a.y) + (a.z + a.w) + (c.x + c.y) + (c.z + c.w);
        #pragma unroll
        for (int o = 1; o < 64; o <<= 1) s += __shfl_xor(s, o);
        float mu = s * (1.0f / D_);
        float dx0 = a.x - mu, dx1 = a.y - mu, dx2 = a.z - mu, dx3 = a.w - mu;
        float dy0 = c.x - mu, dy1 = c.y - mu, dy2 = c.z - mu, dy3 = c.w - mu;
        float s2 = dx0*dx0 + dx1*dx1 + dx2*dx2 + dx3*dx3
                 + dy0*dy0 + dy1*dy1 + dy2*dy2 + dy3*dy3;
        #pragma unroll
        for (int o = 1; o < 64; o <<= 1) s2 += __shfl_xor(s2, o);
        float rs = rsqrtf(s2 * (1.0f / D_) + 1e-5f);
        float4 g1 = *(const float4*)&gamma[l * 4];
        float4 g2 = *(const float4*)&gamma[256 + l * 4];
        float4 b1 = *(const float4*)&beta[l * 4];
        float4 b2 = *(const float4*)&beta[256 + l * 4];
        ushort_t* yr = xn + (size_t)row * D_;
        union { ushort_t us[4]; unsigned long long ll; } o1, o2;
        o1.us[0] = f2bf(dx0 * rs * g1.x + b1.x);
        o1.us[1] = f2bf(dx1 * rs * g1.y + b1.y);
        o1.us[2] = f2bf(dx2 * rs * g1.z + b1.z);
        o1.us[3] = f2bf(dx3 * rs * g1.w + b1.w);
        o2.us[0] = f2bf(dy0 * rs * g2.x + b2.x);
        o2.us[1] = f2bf(dy1 * rs * g2.y + b2.y);
        o2.us[2] = f2bf(dy2 * rs * g2.z + b2.z);
        o2.us[3] = f2bf(dy3 * rs * g2.w + b2.w);
        *(unsigned long long*)(yr + l * 4) = o1.ll;
        *(unsigned long long*)(yr + 256 + l * 4) = o2.ll;
    } else {
        // ---- weight transpose fp32 [K][Nn] -> bf16 [Nn][K] ----
        const float* W; ushort_t* Wt; int Nn, i;
        if (blk < PREP_LN + PREP_WQ) {
            i = blk - PREP_LN; W = Wqkv; Wt = WqkvT; Nn = 1536;
        } else {
            i = blk - (PREP_LN + PREP_WQ); W = Wout; Wt = WoutT; Nn = 512;
        }
        const int nb = Nn >> 5;
        const int bx = (i % nb) * 32, by = (i / nb) * 32;
        const int tx = t & 31, ty = t >> 5;
        float (*tile)[33] = (float(*)[33])smem;
        #pragma unroll
        for (int k = 0; k < 32; k += 8)
            tile[ty + k][tx] = W[(size_t)(by + ty + k) * Nn + bx + tx];
        __syncthreads();
        #pragma unroll
        for (int k = 0; k < 32; k += 8)
            Wt[(size_t)(bx + ty + k) * 512 + by + tx] = f2bf(tile[tx][ty + k]);
    }
}

// ---------------- QKV GEMM v7: 8-wave (512-thr) 128x128 tile, pipelined, XCD-swizzled ----------------
// TLP fix: 512-thread blocks double resident waves/CU (occupancy 17.8% was the limiter).
// Wave tile 64x32 (wr=w>>2, wc=w&3), acc[4][2]. Staging formulas unchanged (t>>2 spans
// 128 rows natively at 512 threads; one gl_lds16 per thread per matrix per step).
#define QKV_BIAS_BLKS 512
__global__ __launch_bounds__(512) void gemm_qkv(const ushort_t* __restrict__ A,
                                                const ushort_t* __restrict__ Bt,
                                                ushort_t* __restrict__ qb,
                                                ushort_t* __restrict__ kb,
                                                ushort_t* __restrict__ vb,
                                                const float* __restrict__ rel,
                                                const int* __restrict__ mask,
                                                ushort_t* __restrict__ bp) {
    const int bid = blockIdx.x;
    const int t = threadIdx.x;

    if (bid < QKV_BIAS_BLKS) {
        // ---- bias+mask pack into [qt][jt][w][nt][quad][m16][k4] order, log2 domain (r8) ----
        const int base = bid * 8192;
        #pragma unroll
        for (int p = 0; p < 4; p++) {
            int idx = base + p * 2048 + t * 4;   // 4 consecutive m, same n
            int n = idx >> 11, m = idx & 2047;
            const int4 mv = *(const int4*)&mask[idx];
            union { ushort_t us[4]; unsigned long long ll; } pkv;
            #pragma unroll
            for (int j = 0; j < 4; j++) {
                int dl = n - (m + j);
                dl = dl < -MAXREL ? -MAXREL : (dl > MAXREL ? MAXREL : dl);
                int mj = (j == 0) ? mv.x : (j == 1) ? mv.y : (j == 2) ? mv.z : mv.w;
                float v = (mj == 0) ? -1e9f : rel[dl + MAXREL] * LOG2E;
                pkv.us[j] = f2bf(v);
            }
            int off = ((n >> 7) << 18) + ((m >> 6) << 13) + (((n >> 4) & 7) << 10)
                    + (((m >> 4) & 3) << 8) + (((m >> 2) & 3) << 6) + ((n & 15) << 2);
            *(unsigned long long*)(bp + off) = pkv.ll;
        }
        return;
    }

    __shared__ ushort_t As[2][4096];         // 16KB (also reused as v-restage buffer)
    __shared__ ushort_t Bs[2][4096];         // 16KB
    const int g = bid - QKV_BIAS_BLKS;       // 0..767
    // XCD swizzle: XCD(bid) = bid%8 (heuristic); give each XCD 96 contiguous tiles
    const int tid = (g & 7) * 96 + (g >> 3);
    const int lane = t & 63, w = t >> 6;
    const int m16 = lane & 15, quad = lane >> 4;
    const int wr = w >> 2, wc = w & 3;       // 2x4 wave grid, wave tile 64 rows x 32 cols
    const int r0 = (tid / 12) * 128, c0 = (tid % 12) * 128;

    const ushort_t* Ag = A  + (size_t)(r0 + (t >> 2)) * D_ + (t & 3) * 8;
    const ushort_t* Bg = Bt + (size_t)(c0 + (t >> 2)) * D_ + (t & 3) * 8;

    f32x4 acc[4][2];
    #pragma unroll
    for (int i = 0; i < 4; i++)
        #pragma unroll
        for (int j = 0; j < 2; j++) acc[i][j] = (f32x4){0.f, 0.f, 0.f, 0.f};

    // prologue: stage k0=0 into buf 0 (each thread: 16B of A + 16B of B)
    gl_lds16(Ag, As[0] + w * 512);
    gl_lds16(Bg, Bs[0] + w * 512);
    __syncthreads();

    for (int k0 = 0; k0 < D_; k0 += 32) {
        const int buf = (k0 >> 5) & 1;
        if (k0 + 32 < D_) {                  // issue next-step loads BEFORE compute
            gl_lds16(Ag + k0 + 32, As[buf ^ 1] + w * 512);
            gl_lds16(Bg + k0 + 32, Bs[buf ^ 1] + w * 512);
        }
        bf16x8 af[4], bfr[2];
        #pragma unroll
        for (int rt = 0; rt < 4; rt++)
            af[rt] = *(const bf16x8*)(As[buf] + (wr * 64 + rt * 16 + m16) * 32 + quad * 8);
        #pragma unroll
        for (int ct = 0; ct < 2; ct++)
            bfr[ct] = *(const bf16x8*)(Bs[buf] + (wc * 32 + ct * 16 + m16) * 32 + quad * 8);
        #pragma unroll
        for (int rt = 0; rt < 4; rt++)
            #pragma unroll
            for (int ct = 0; ct < 2; ct++)
                acc[rt][ct] = __builtin_amdgcn_mfma_f32_16x16x32_bf16(af[rt], bfr[ct], acc[rt][ct], 0, 0, 0);
        __syncthreads();                     // one barrier/step: drains loads into buf^1
    }

    const int b_blk = r0 >> 11, n_base = r0 & 2047;
    if ((c0 >> 9) == 2) {
        // ---- V epilogue: LDS restage, 256B-contiguous stores along n ----
        ushort_t* SH = As[0];                // 16KB contiguous (64 dcols x 128 n)
        #pragma unroll
        for (int ph = 0; ph < 2; ph++) {
            if (ph) __syncthreads();
            if ((wc >> 1) == ph) {
                #pragma unroll
                for (int ct = 0; ct < 2; ct++) {
                    int dcol = (wc & 1) * 32 + ct * 16 + m16;
                    #pragma unroll
                    for (int rt = 0; rt < 4; rt++) {
                        int nl = wr * 64 + rt * 16 + quad * 4;
                        union { ushort_t us[4]; unsigned long long ll; } pkv;
                        #pragma unroll
                        for (int r = 0; r < 4; r++) pkv.us[r] = f2bf(acc[rt][ct][r]);
                        *(unsigned long long*)(&SH[dcol * 128 + (nl ^ ((dcol & 7) << 3))]) = pkv.ll;
                    }
                }
            }
            __syncthreads();
            int h = ((c0 + ph * 64) >> 6) & 7;
            #pragma unroll
            for (int p = 0; p < 2; p++) {
                int dr = p * 32 + (t >> 4);
                int n0 = (t & 15) * 8;
                bf16x8 vv = *(const bf16x8*)&SH[dr * 128 + (n0 ^ ((dr & 7) << 3))];
                *(bf16x8*)(vb + ((size_t)(b_blk * H_ + h) * 64 + dr) * N_ + n_base + n0) = vv;
            }
        }
    } else {
        // ---- q/k epilogue (32B-run scalar stores) ----
        #pragma unroll
        for (int ct = 0; ct < 2; ct++) {
            int cc = c0 + wc * 32 + ct * 16;
            int which = cc >> 9;
            int h = (cc >> 6) & 7;
            int d = (cc & 63) + m16;
            #pragma unroll
            for (int rt = 0; rt < 4; rt++) {
                int rowb = r0 + wr * 64 + rt * 16 + quad * 4;
                int b = rowb >> 11, n0 = rowb & 2047;
                if (which == 0) {
                    #pragma unroll
                    for (int r = 0; r < 4; r++)
                        qb[((size_t)((b * H_ + h) * N_ + n0 + r)) * 64 + d] = f2bf(acc[rt][ct][r] * (0.125f * LOG2E));
                } else {
                    #pragma unroll
                    for (int r = 0; r < 4; r++)
                        kb[((size_t)((b * H_ + h) * N_ + n0 + r)) * 64 + d] = f2bf(acc[rt][ct][r]);
                }
            }
        }
    }
}

// ---------------- Out-proj v5: 8-wave (512-thr) 64x128 tile, pipelined, XCD-swizzled ----------------
__global__ __launch_bounds__(512) void gemm_out(const ushort_t* __restrict__ A,
                                                const ushort_t* __restrict__ Bt,
                                                const float* __restrict__ bias,
                                                float* __restrict__ C) {
    __shared__ ushort_t As[2][2048];
    __shared__ ushort_t Bs[2][4096];
    const int t = threadIdx.x;
    const int lane = t & 63, w = t >> 6;
    const int m16 = lane & 15, quad = lane >> 4;
    const int wr = w >> 2, wc = w & 3;        // 2x4 wave grid, wave tile 32 rows x 32 cols
    // XCD swizzle: 512 = 8 XCDs x 64 tiles; each XCD owns 16 contiguous 64-row A-panels
    const int bswz = (blockIdx.x & 7) * 64 + (blockIdx.x >> 3);
    const int r0 = (bswz >> 2) * 64, c0 = (bswz & 3) * 128;

    // A: 64 rows x 64B -> 256 lanes (waves 0-3); B: 128 rows x 64B -> all 512 threads
    const ushort_t* Ag = A  + (size_t)(r0 + (t >> 2)) * D_ + (t & 3) * 8;   // valid for t<256
    const ushort_t* Bg = Bt + (size_t)(c0 + (t >> 2)) * D_ + (t & 3) * 8;

    f32x4 acc[2][2];
    #pragma unroll
    for (int i = 0; i < 2; i++)
        #pragma unroll
        for (int j = 0; j < 2; j++) acc[i][j] = (f32x4){0.f, 0.f, 0.f, 0.f};

    // prologue
    if (w < 4) gl_lds16(Ag, As[0] + w * 512);
    gl_lds16(Bg, Bs[0] + w * 512);
    __syncthreads();

    for (int k0 = 0; k0 < D_; k0 += 32) {
        const int buf = (k0 >> 5) & 1;
        if (k0 + 32 < D_) {
            if (w < 4) gl_lds16(Ag + k0 + 32, As[buf ^ 1] + w * 512);
            gl_lds16(Bg + k0 + 32, Bs[buf ^ 1] + w * 512);
        }
        bf16x8 af[2], bfr[2];
        #pragma unroll
        for (int mf = 0; mf < 2; mf++)
            af[mf] = *(const bf16x8*)(As[buf] + (wr * 32 + mf * 16 + m16) * 32 + quad * 8);
        #pragma unroll
        for (int nt = 0; nt < 2; nt++)
            bfr[nt] = *(const bf16x8*)(Bs[buf] + (wc * 32 + nt * 16 + m16) * 32 + quad * 8);
        #pragma unroll
        for (int mf = 0; mf < 2; mf++)
            #pragma unroll
            for (int nt = 0; nt < 2; nt++)
                acc[mf][nt] = __builtin_amdgcn_mfma_f32_16x16x32_bf16(af[mf], bfr[nt], acc[mf][nt], 0, 0, 0);
        __syncthreads();
    }

    #pragma unroll
    for (int mf = 0; mf < 2; mf++) {
        #pragma unroll
        for (int nt = 0; nt < 2; nt++) {
            int col = c0 + wc * 32 + nt * 16 + m16;
            int row0 = r0 + wr * 32 + mf * 16 + quad * 4;
            float bv = bias[col];
            #pragma unroll
            for (int r = 0; r < 4; r++)
                C[(size_t)(row0 + r) * 512 + col] = acc[mf][nt][r] + bv;
        }
    }
}

// ---------------- MFMA flash attention v11 (r9-verified): rsum via MFMA-with-ones ----------------
#define ATTN_TILE(JT, KCUR, VCUR, KNXT, VNXT, BCUR, BNXT)                              \
  {                                                                                    \
    const int jt = (JT);                                                               \
    const int buf = jt & 1;                                                            \
    if (jt + 2 < 32) {                                                                 \
      KNXT = *(const bf16x8*)(kgbase + (size_t)((jt + 2) * 64 + srow) * 64 + scb * 8); \
      VNXT = *(const bf16x8*)(vgbase + (size_t)srow * N_ + (jt + 2) * 64 + scb * 8);   \
    }                                                                                  \
    if (jt + 1 < 32) {                                                                 \
      _Pragma("unroll")                                                                \
      for (int nt = 0; nt < 4; nt++)                                                   \
        BNXT[nt] = *(const bf16x4*)(bpb + ((jt + 1) << 13) + (nt << 8));               \
    }                                                                                  \
    unsigned pk[8];                                                                    \
    __builtin_amdgcn_s_setprio(1);                                                     \
    _Pragma("unroll")                                                                  \
    for (int nt = 0; nt < 4; nt++) {                                                   \
      f32x4 a2;                                                                        \
      _Pragma("unroll")                                                                \
      for (int r = 0; r < 4; r++) a2[r] = bf2f((ushort_t)BCUR[nt][r]);                 \
      int kr = nt * 16 + m16;                                                          \
      bf16x8 kf0 = *(const bf16x8*)(&Ks[buf][kr * 64 + ((quad) ^ (kr & 7)) * 8]);      \
      bf16x8 kf1 = *(const bf16x8*)(&Ks[buf][kr * 64 + ((quad + 4) ^ (kr & 7)) * 8]);  \
      a2 = __builtin_amdgcn_mfma_f32_16x16x32_bf16(kf0, qa0, a2, 0, 0, 0);             \
      a2 = __builtin_amdgcn_mfma_f32_16x16x32_bf16(kf1, qa1, a2, 0, 0, 0);             \
      float p0 = fexp2(a2[0]), p1 = fexp2(a2[1]);                                      \
      float p2 = fexp2(a2[2]), p3 = fexp2(a2[3]);                                      \
      pk[nt * 2]     = cvt_pk_bf16(p0, p1);                                            \
      pk[nt * 2 + 1] = cvt_pk_bf16(p2, p3);                                            \
    }                                                                                  \
    __builtin_amdgcn_s_setprio(0);                                                     \
    _Pragma("unroll")                                                                  \
    for (int i = 0; i < 4; i++) {                                                      \
      int chunk = 2 * i + (quad >> 1);                                                 \
      union { unsigned uu[2]; unsigned long long ll; } wrp;                            \
      wrp.uu[0] = pk[2 * i]; wrp.uu[1] = pk[2 * i + 1];                                \
      *(unsigned long long*)(pw + m16 * 64 + ((chunk ^ (m16 & 7)) << 3)                \
                             + (quad & 1) * 4) = wrp.ll;                               \
    }                                                                                  \
    bf16x8 pa0 = *(const bf16x8*)(pw + m16 * 64 + ((quad ^ (m16 & 7)) << 3));          \
    bf16x8 pa1 = *(const bf16x8*)(pw + m16 * 64 + (((quad + 4) ^ (m16 & 7)) << 3));    \
    __builtin_amdgcn_s_setprio(1);                                                     \
    rs = __builtin_amdgcn_mfma_f32_16x16x32_bf16(pa0, kones, rs, 0, 0, 0);             \
    rs = __builtin_amdgcn_mfma_f32_16x16x32_bf16(pa1, kones, rs, 0, 0, 0);             \
    _Pragma("unroll")                                                                  \
    for (int nt = 0; nt < 4; nt++) {                                                   \
      int d = nt * 16 + m16;                                                           \
      bf16x8 vf0 = *(const bf16x8*)(&Vs[buf][d * 64 + ((quad) ^ (d & 7)) * 8]);        \
      bf16x8 vf1 = *(const bf16x8*)(&Vs[buf][d * 64 + ((quad + 4) ^ (d & 7)) * 8]);    \
      o[nt] = __builtin_amdgcn_mfma_f32_16x16x32_bf16(pa0, vf0, o[nt], 0, 0, 0);       \
      o[nt] = __builtin_amdgcn_mfma_f32_16x16x32_bf16(pa1, vf1, o[nt], 0, 0, 0);       \
    }                                                                                  \
    __builtin_amdgcn_s_setprio(0);                                                     \
    if (jt + 1 < 32) {                                                                 \
      *(bf16x8*)(&Ks[buf ^ 1][soff]) = KCUR;                                           \
      *(bf16x8*)(&Vs[buf ^ 1][soff]) = VCUR;                                           \
    }                                                                                  \
    __syncthreads();                                                                   \
  }

__global__ __launch_bounds__(512, 4) void attn_mfma(const ushort_t* __restrict__ qb,
                                                    const ushort_t* __restrict__ kb,
                                                    const ushort_t* __restrict__ vb,
                                                    const ushort_t* __restrict__ bp,
                                                    ushort_t* __restrict__ attn) {
    __shared__ ushort_t Ks[2][64 * 64];      // [buf][key][d] swizzled, 8KB each
    __shared__ ushort_t Vs[2][64 * 64];      // [buf][d][key] swizzled, 8KB each
    __shared__ ushort_t p_s[8][16 * 64];     // [wave][qrow][key] swizzled, 16KB

    const int t = threadIdx.x;
    const int w = t >> 6, lane = t & 63;
    const int m16 = lane & 15, quad = lane >> 4;
    const int id = blockIdx.x;
    const int bh = id & 31;                  // XCD = id%8 = bh%8 (heuristic)
    const int qt = id >> 5;
    const int b = bh >> 3, h = bh & 7;
    const int n0w = qt * 128 + w * 16;

    // staging: thread stages exactly one 8-elem chunk of K and of V per tile
    const int srow = t >> 3, scb = t & 7;
    const int soff = srow * 64 + (scb ^ (srow & 7)) * 8;
    const ushort_t* kgbase = kb + ((size_t)bh * N_) * 64;   // [key][d]
    const ushort_t* vgbase = vb + ((size_t)bh * 64) * N_;   // [d][key]

    // Q frags (one 16-row m-frag per wave)
    const ushort_t* qpb = qb + ((size_t)(bh * N_ + n0w + m16)) * 64 + quad * 8;
    bf16x8 qa0 = *(const bf16x8*)(qpb);
    bf16x8 qa1 = *(const bf16x8*)(qpb + 32);

    // bias packed [qt][jt][w][nt][quad][m16][k4]; per phase the 16 m16-lanes read 128B contiguous
    const ushort_t* bpb = bp + ((size_t)qt << 18) + (w << 10) + (quad << 6) + (m16 << 2);

    // all-ones bf16 B-frag for the rowsum MFMA (layout-invariant)
    bf16x8 kones;
    #pragma unroll
    for (int i = 0; i < 8; i++) kones[i] = (short)0x3F80;

    // prologue: stage tile 0 into buf 0; prefetch tile 1 (regs) and bias jt=0 (regs)
    *(bf16x8*)(&Ks[0][soff]) = *(const bf16x8*)(kgbase + (size_t)srow * 64 + scb * 8);
    *(bf16x8*)(&Vs[0][soff]) = *(const bf16x8*)(vgbase + (size_t)srow * N_ + scb * 8);
    bf16x8 kA = *(const bf16x8*)(kgbase + (size_t)(64 + srow) * 64 + scb * 8);
    bf16x8 vA = *(const bf16x8*)(vgbase + (size_t)srow * N_ + 64 + scb * 8);
    bf16x8 kB, vB;
    bf16x4 bA[4], bB[4];
    #pragma unroll
    for (int nt = 0; nt < 4; nt++) bA[nt] = *(const bf16x4*)(bpb + (nt << 8));
    __syncthreads();

    f32x4 o[4];
    #pragma unroll
    for (int nt = 0; nt < 4; nt++) o[nt] = (f32x4){0.f, 0.f, 0.f, 0.f};
    f32x4 rs = (f32x4){0.f, 0.f, 0.f, 0.f};

    ushort_t* pw = p_s[w];

    for (int jt2 = 0; jt2 < 16; jt2++) {
        ATTN_TILE(2 * jt2,     kA, vA, kB, vB, bA, bB);
        ATTN_TILE(2 * jt2 + 1, kB, vB, kA, vA, bB, bA);
    }

    // ---- normalize + store: o[nt][r] is (qrow=quad*4+r, d=nt*16+m16); rs[r] = rowsum(qrow) ----
    #pragma unroll
    for (int r = 0; r < 4; r++) {
        float inv = 1.0f / rs[r];
        int n = n0w + quad * 4 + r;
        ushort_t* orow = attn + ((size_t)(b * N_ + n)) * 512 + h * 64 + m16;
        #pragma unroll
        for (int nt = 0; nt < 4; nt++) orow[nt * 16] = f2bf(o[nt][r] * inv);
    }
}

extern "C" void kernel_launch(void* const* d_in, const int* in_sizes, int n_in,
                              void* d_out, int out_size, void* d_ws, size_t ws_size,
                              hipStream_t stream) {
    const float* x     = (const float*)d_in[0];
    const float* gamma = (const float*)d_in[1];
    const float* beta  = (const float*)d_in[2];
    const float* Wqkv  = (const float*)d_in[3];
    const float* Wout  = (const float*)d_in[4];
    const float* bout  = (const float*)d_in[5];
    const float* rel   = (const float*)d_in[6];
    const int*   mask  = (const int*)d_in[7];
    float* out = (float*)d_out;

    char* wsb = (char*)d_ws;
    ushort_t* xn    = (ushort_t*)(wsb);                    //  8 MB
    ushort_t* attnb = (ushort_t*)(wsb + ( 8u << 20));      //  8 MB
    ushort_t* qb    = (ushort_t*)(wsb + (16u << 20));      //  8 MB
    ushort_t* kb    = (ushort_t*)(wsb + (24u << 20));      //  8 MB
    ushort_t* vb    = (ushort_t*)(wsb + (32u << 20));      //  8 MB
    ushort_t* WqkvT = (ushort_t*)(wsb + (40u << 20));      //  1.5 MB
    ushort_t* WoutT = (ushort_t*)(wsb + (42u << 20));      //  0.5 MB
    ushort_t* bp    = (ushort_t*)(wsb + (44u << 20));      //  8 MB

    // 1. prep: layernorm + both weight transposes
    prep_kernel<<<PREP_LN + PREP_WQ + PREP_WO, 256, 0, stream>>>(
        x, gamma, beta, xn, Wqkv, WqkvT, Wout, WoutT);

    // 2. QKV projection (8-wave pipelined MFMA, XCD-swizzled) + concurrent bias-pack blocks
    gemm_qkv<<<QKV_BIAS_BLKS + 768, 512, 0, stream>>>(xn, WqkvT, qb, kb, vb, rel, mask, bp);

    // 3. MFMA flash attention v11 -> bf16
    attn_mfma<<<512, 512, 0, stream>>>(qb, kb, vb, bp, attnb);

    // 4. output projection + bias (8-wave pipelined MFMA, XCD-swizzled) -> fp32
    gemm_out<<<512, 512, 0, stream>>>(attnb, WoutT, bout, out);
}

// Round 18
// 182.771 us; speedup vs baseline: 1.0719x; 1.0223x over previous
//
#include <hip/hip_runtime.h>

typedef __attribute__((ext_vector_type(8))) short bf16x8;
typedef __attribute__((ext_vector_type(4))) short bf16x4;
typedef __attribute__((ext_vector_type(4))) float f32x4;
typedef unsigned short ushort_t;

#define B_ 4
#define H_ 8
#define N_ 2048
#define D_ 512
#define MAXREL 199   // MAX_REL-1
#define LOG2E 1.4426950408889634f

__device__ __forceinline__ ushort_t f2bf(float f) {
    union { float f; unsigned u; } v; v.f = f;
    unsigned r = v.u + 0x7fffu + ((v.u >> 16) & 1u);
    return (ushort_t)(r >> 16);
}
__device__ __forceinline__ float bf2f(ushort_t u) {
    union { unsigned u; float f; } v; v.u = ((unsigned)u) << 16;
    return v.f;
}
__device__ __forceinline__ float fexp2(float x) {
#if __has_builtin(__builtin_amdgcn_exp2f)
    return __builtin_amdgcn_exp2f(x);
#else
    return __expf(x * 0.6931471805599453f);
#endif
}
__device__ __forceinline__ unsigned cvt_pk_bf16(float lo, float hi) {
    unsigned r;
    asm("v_cvt_pk_bf16_f32 %0, %1, %2" : "=v"(r) : "v"(lo), "v"(hi));
    return r;
}
// async global->LDS, 16B per lane; lds dest = wave-uniform base + lane*16
__device__ __forceinline__ void gl_lds16(const ushort_t* g, ushort_t* l) {
    __builtin_amdgcn_global_load_lds(
        (const __attribute__((address_space(1))) void*)g,
        (__attribute__((address_space(3))) void*)l,
        16, 0, 0);
}

// ---------------- prep v3: layernorm (wave-per-row) | wtrans(Wqkv) | wtrans(Wout) ----------------
#define PREP_LN    2048                     // (B*N)/4 rows
#define PREP_WQ    768                      // (1536/32)*(512/32)
#define PREP_WO    256                      // (512/32)*(512/32)
__global__ __launch_bounds__(256) void prep_kernel(const float* __restrict__ x,
                                                   const float* __restrict__ gamma,
                                                   const float* __restrict__ beta,
                                                   ushort_t* __restrict__ xn,
                                                   const float* __restrict__ Wqkv,
                                                   ushort_t* __restrict__ WqkvT,
                                                   const float* __restrict__ Wout,
                                                   ushort_t* __restrict__ WoutT) {
    __shared__ float smem[32 * 33];
    const int blk = blockIdx.x;
    const int t = threadIdx.x;

    if (blk < PREP_LN) {
        // ---- LayerNorm: one 64-lane wave per row, float4 loads, butterfly reduce (verified r6) ----
        const int row = blk * 4 + (t >> 6);
        const int l = t & 63;
        const float* xr = x + (size_t)row * D_;
        float4 a = *(const float4*)&xr[l * 4];
        float4 c = *(const float4*)&xr[256 + l * 4];
        float s = (a.x + a.y) + (a.z + a.w) + (c.x + c.y) + (c.z + c.w);
        #pragma unroll
        for (int o = 1; o < 64; o <<= 1) s += __shfl_xor(s, o);
        float mu = s * (1.0f / D_);
        float dx0 = a.x - mu, dx1 = a.y - mu, dx2 = a.z - mu, dx3 = a.w - mu;
        float dy0 = c.x - mu, dy1 = c.y - mu, dy2 = c.z - mu, dy3 = c.w - mu;
        float s2 = dx0*dx0 + dx1*dx1 + dx2*dx2 + dx3*dx3
                 + dy0*dy0 + dy1*dy1 + dy2*dy2 + dy3*dy3;
        #pragma unroll
        for (int o = 1; o < 64; o <<= 1) s2 += __shfl_xor(s2, o);
        float rs = rsqrtf(s2 * (1.0f / D_) + 1e-5f);
        float4 g1 = *(const float4*)&gamma[l * 4];
        float4 g2 = *(const float4*)&gamma[256 + l * 4];
        float4 b1 = *(const float4*)&beta[l * 4];
        float4 b2 = *(const float4*)&beta[256 + l * 4];
        ushort_t* yr = xn + (size_t)row * D_;
        union { ushort_t us[4]; unsigned long long ll; } o1, o2;
        o1.us[0] = f2bf(dx0 * rs * g1.x + b1.x);
        o1.us[1] = f2bf(dx1 * rs * g1.y + b1.y);
        o1.us[2] = f2bf(dx2 * rs * g1.z + b1.z);
        o1.us[3] = f2bf(dx3 * rs * g1.w + b1.w);
        o2.us[0] = f2bf(dy0 * rs * g2.x + b2.x);
        o2.us[1] = f2bf(dy1 * rs * g2.y + b2.y);
        o2.us[2] = f2bf(dy2 * rs * g2.z + b2.z);
        o2.us[3] = f2bf(dy3 * rs * g2.w + b2.w);
        *(unsigned long long*)(yr + l * 4) = o1.ll;
        *(unsigned long long*)(yr + 256 + l * 4) = o2.ll;
    } else {
        // ---- weight transpose fp32 [K][Nn] -> bf16 [Nn][K] ----
        const float* W; ushort_t* Wt; int Nn, i;
        if (blk < PREP_LN + PREP_WQ) {
            i = blk - PREP_LN; W = Wqkv; Wt = WqkvT; Nn = 1536;
        } else {
            i = blk - (PREP_LN + PREP_WQ); W = Wout; Wt = WoutT; Nn = 512;
        }
        const int nb = Nn >> 5;
        const int bx = (i % nb) * 32, by = (i / nb) * 32;
        const int tx = t & 31, ty = t >> 5;
        float (*tile)[33] = (float(*)[33])smem;
        #pragma unroll
        for (int k = 0; k < 32; k += 8)
            tile[ty + k][tx] = W[(size_t)(by + ty + k) * Nn + bx + tx];
        __syncthreads();
        #pragma unroll
        for (int k = 0; k < 32; k += 8)
            Wt[(size_t)(bx + ty + k) * 512 + by + tx] = f2bf(tile[tx][ty + k]);
    }
}

// ---------------- QKV GEMM v7 (r12-verified): 8-wave 128x128, pipelined, XCD-swizzled ----------------
#define QKV_BIAS_BLKS 512
__global__ __launch_bounds__(512) void gemm_qkv(const ushort_t* __restrict__ A,
                                                const ushort_t* __restrict__ Bt,
                                                ushort_t* __restrict__ qb,
                                                ushort_t* __restrict__ kb,
                                                ushort_t* __restrict__ vb,
                                                const float* __restrict__ rel,
                                                const int* __restrict__ mask,
                                                ushort_t* __restrict__ bp) {
    const int bid = blockIdx.x;
    const int t = threadIdx.x;

    if (bid < QKV_BIAS_BLKS) {
        // ---- bias+mask pack into [qt][jt][w][nt][quad][m16][k4] order, log2 domain (r8) ----
        const int base = bid * 8192;
        #pragma unroll
        for (int p = 0; p < 4; p++) {
            int idx = base + p * 2048 + t * 4;   // 4 consecutive m, same n
            int n = idx >> 11, m = idx & 2047;
            const int4 mv = *(const int4*)&mask[idx];
            union { ushort_t us[4]; unsigned long long ll; } pkv;
            #pragma unroll
            for (int j = 0; j < 4; j++) {
                int dl = n - (m + j);
                dl = dl < -MAXREL ? -MAXREL : (dl > MAXREL ? MAXREL : dl);
                int mj = (j == 0) ? mv.x : (j == 1) ? mv.y : (j == 2) ? mv.z : mv.w;
                float v = (mj == 0) ? -1e9f : rel[dl + MAXREL] * LOG2E;
                pkv.us[j] = f2bf(v);
            }
            int off = ((n >> 7) << 18) + ((m >> 6) << 13) + (((n >> 4) & 7) << 10)
                    + (((m >> 4) & 3) << 8) + (((m >> 2) & 3) << 6) + ((n & 15) << 2);
            *(unsigned long long*)(bp + off) = pkv.ll;
        }
        return;
    }

    __shared__ ushort_t As[2][4096];         // 16KB (also reused as v-restage buffer)
    __shared__ ushort_t Bs[2][4096];         // 16KB
    const int g = bid - QKV_BIAS_BLKS;       // 0..767
    const int tid = (g & 7) * 96 + (g >> 3); // XCD swizzle
    const int lane = t & 63, w = t >> 6;
    const int m16 = lane & 15, quad = lane >> 4;
    const int wr = w >> 2, wc = w & 3;       // 2x4 wave grid, wave tile 64 rows x 32 cols
    const int r0 = (tid / 12) * 128, c0 = (tid % 12) * 128;

    const ushort_t* Ag = A  + (size_t)(r0 + (t >> 2)) * D_ + (t & 3) * 8;
    const ushort_t* Bg = Bt + (size_t)(c0 + (t >> 2)) * D_ + (t & 3) * 8;

    f32x4 acc[4][2];
    #pragma unroll
    for (int i = 0; i < 4; i++)
        #pragma unroll
        for (int j = 0; j < 2; j++) acc[i][j] = (f32x4){0.f, 0.f, 0.f, 0.f};

    gl_lds16(Ag, As[0] + w * 512);
    gl_lds16(Bg, Bs[0] + w * 512);
    __syncthreads();

    for (int k0 = 0; k0 < D_; k0 += 32) {
        const int buf = (k0 >> 5) & 1;
        if (k0 + 32 < D_) {                  // issue next-step loads BEFORE compute
            gl_lds16(Ag + k0 + 32, As[buf ^ 1] + w * 512);
            gl_lds16(Bg + k0 + 32, Bs[buf ^ 1] + w * 512);
        }
        bf16x8 af[4], bfr[2];
        #pragma unroll
        for (int rt = 0; rt < 4; rt++)
            af[rt] = *(const bf16x8*)(As[buf] + (wr * 64 + rt * 16 + m16) * 32 + quad * 8);
        #pragma unroll
        for (int ct = 0; ct < 2; ct++)
            bfr[ct] = *(const bf16x8*)(Bs[buf] + (wc * 32 + ct * 16 + m16) * 32 + quad * 8);
        #pragma unroll
        for (int rt = 0; rt < 4; rt++)
            #pragma unroll
            for (int ct = 0; ct < 2; ct++)
                acc[rt][ct] = __builtin_amdgcn_mfma_f32_16x16x32_bf16(af[rt], bfr[ct], acc[rt][ct], 0, 0, 0);
        __syncthreads();
    }

    const int b_blk = r0 >> 11, n_base = r0 & 2047;
    if ((c0 >> 9) == 2) {
        // ---- V epilogue: LDS restage, 256B-contiguous stores along n ----
        ushort_t* SH = As[0];                // 16KB contiguous (64 dcols x 128 n)
        #pragma unroll
        for (int ph = 0; ph < 2; ph++) {
            if (ph) __syncthreads();
            if ((wc >> 1) == ph) {
                #pragma unroll
                for (int ct = 0; ct < 2; ct++) {
                    int dcol = (wc & 1) * 32 + ct * 16 + m16;
                    #pragma unroll
                    for (int rt = 0; rt < 4; rt++) {
                        int nl = wr * 64 + rt * 16 + quad * 4;
                        union { ushort_t us[4]; unsigned long long ll; } pkv;
                        #pragma unroll
                        for (int r = 0; r < 4; r++) pkv.us[r] = f2bf(acc[rt][ct][r]);
                        *(unsigned long long*)(&SH[dcol * 128 + (nl ^ ((dcol & 7) << 3))]) = pkv.ll;
                    }
                }
            }
            __syncthreads();
            int h = ((c0 + ph * 64) >> 6) & 7;
            #pragma unroll
            for (int p = 0; p < 2; p++) {
                int dr = p * 32 + (t >> 4);
                int n0 = (t & 15) * 8;
                bf16x8 vv = *(const bf16x8*)&SH[dr * 128 + (n0 ^ ((dr & 7) << 3))];
                *(bf16x8*)(vb + ((size_t)(b_blk * H_ + h) * 64 + dr) * N_ + n_base + n0) = vv;
            }
        }
    } else {
        // ---- q/k epilogue (32B-run scalar stores) ----
        #pragma unroll
        for (int ct = 0; ct < 2; ct++) {
            int cc = c0 + wc * 32 + ct * 16;
            int which = cc >> 9;
            int h = (cc >> 6) & 7;
            int d = (cc & 63) + m16;
            #pragma unroll
            for (int rt = 0; rt < 4; rt++) {
                int rowb = r0 + wr * 64 + rt * 16 + quad * 4;
                int b = rowb >> 11, n0 = rowb & 2047;
                if (which == 0) {
                    #pragma unroll
                    for (int r = 0; r < 4; r++)
                        qb[((size_t)((b * H_ + h) * N_ + n0 + r)) * 64 + d] = f2bf(acc[rt][ct][r] * (0.125f * LOG2E));
                } else {
                    #pragma unroll
                    for (int r = 0; r < 4; r++)
                        kb[((size_t)((b * H_ + h) * N_ + n0 + r)) * 64 + d] = f2bf(acc[rt][ct][r]);
                }
            }
        }
    }
}

// ---------------- Out-proj v5 (r12-verified): 8-wave 64x128, pipelined, XCD-swizzled ----------------
__global__ __launch_bounds__(512) void gemm_out(const ushort_t* __restrict__ A,
                                                const ushort_t* __restrict__ Bt,
                                                const float* __restrict__ bias,
                                                float* __restrict__ C) {
    __shared__ ushort_t As[2][2048];
    __shared__ ushort_t Bs[2][4096];
    const int t = threadIdx.x;
    const int lane = t & 63, w = t >> 6;
    const int m16 = lane & 15, quad = lane >> 4;
    const int wr = w >> 2, wc = w & 3;        // 2x4 wave grid, wave tile 32 rows x 32 cols
    // XCD swizzle: 512 = 8 XCDs x 64 tiles; each XCD owns 16 contiguous 64-row A-panels
    const int bswz = (blockIdx.x & 7) * 64 + (blockIdx.x >> 3);
    const int r0 = (bswz >> 2) * 64, c0 = (bswz & 3) * 128;

    // A: 64 rows x 64B -> 256 lanes (waves 0-3); B: 128 rows x 64B -> all 512 threads
    const ushort_t* Ag = A  + (size_t)(r0 + (t >> 2)) * D_ + (t & 3) * 8;   // valid for t<256
    const ushort_t* Bg = Bt + (size_t)(c0 + (t >> 2)) * D_ + (t & 3) * 8;

    f32x4 acc[2][2];
    #pragma unroll
    for (int i = 0; i < 2; i++)
        #pragma unroll
        for (int j = 0; j < 2; j++) acc[i][j] = (f32x4){0.f, 0.f, 0.f, 0.f};

    // prologue
    if (w < 4) gl_lds16(Ag, As[0] + w * 512);
    gl_lds16(Bg, Bs[0] + w * 512);
    __syncthreads();

    for (int k0 = 0; k0 < D_; k0 += 32) {
        const int buf = (k0 >> 5) & 1;
        if (k0 + 32 < D_) {
            if (w < 4) gl_lds16(Ag + k0 + 32, As[buf ^ 1] + w * 512);
            gl_lds16(Bg + k0 + 32, Bs[buf ^ 1] + w * 512);
        }
        bf16x8 af[2], bfr[2];
        #pragma unroll
        for (int mf = 0; mf < 2; mf++)
            af[mf] = *(const bf16x8*)(As[buf] + (wr * 32 + mf * 16 + m16) * 32 + quad * 8);
        #pragma unroll
        for (int nt = 0; nt < 2; nt++)
            bfr[nt] = *(const bf16x8*)(Bs[buf] + (wc * 32 + nt * 16 + m16) * 32 + quad * 8);
        #pragma unroll
        for (int mf = 0; mf < 2; mf++)
            #pragma unroll
            for (int nt = 0; nt < 2; nt++)
                acc[mf][nt] = __builtin_amdgcn_mfma_f32_16x16x32_bf16(af[mf], bfr[nt], acc[mf][nt], 0, 0, 0);
        __syncthreads();
    }

    #pragma unroll
    for (int mf = 0; mf < 2; mf++) {
        #pragma unroll
        for (int nt = 0; nt < 2; nt++) {
            int col = c0 + wc * 32 + nt * 16 + m16;
            int row0 = r0 + wr * 32 + mf * 16 + quad * 4;
            float bv = bias[col];
            #pragma unroll
            for (int r = 0; r < 4; r++)
                C[(size_t)(row0 + r) * 512 + col] = acc[mf][nt][r] + bv;
        }
    }
}

// ---------------- MFMA flash attention v11 (r9/r11/r12-verified): rsum via MFMA-with-ones ----------------
#define ATTN_TILE(JT, KCUR, VCUR, KNXT, VNXT, BCUR, BNXT)                              \
  {                                                                                    \
    const int jt = (JT);                                                               \
    const int buf = jt & 1;                                                            \
    if (jt + 2 < 32) {                                                                 \
      KNXT = *(const bf16x8*)(kgbase + (size_t)((jt + 2) * 64 + srow) * 64 + scb * 8); \
      VNXT = *(const bf16x8*)(vgbase + (size_t)srow * N_ + (jt + 2) * 64 + scb * 8);   \
    }                                                                                  \
    if (jt + 1 < 32) {                                                                 \
      _Pragma("unroll")                                                                \
      for (int nt = 0; nt < 4; nt++)                                                   \
        BNXT[nt] = *(const bf16x4*)(bpb + ((jt + 1) << 13) + (nt << 8));               \
    }                                                                                  \
    unsigned pk[8];                                                                    \
    __builtin_amdgcn_s_setprio(1);                                                     \
    _Pragma("unroll")                                                                  \
    for (int nt = 0; nt < 4; nt++) {                                                   \
      f32x4 a2;                                                                        \
      _Pragma("unroll")                                                                \
      for (int r = 0; r < 4; r++) a2[r] = bf2f((ushort_t)BCUR[nt][r]);                 \
      int kr = nt * 16 + m16;                                                          \
      bf16x8 kf0 = *(const bf16x8*)(&Ks[buf][kr * 64 + ((quad) ^ (kr & 7)) * 8]);      \
      bf16x8 kf1 = *(const bf16x8*)(&Ks[buf][kr * 64 + ((quad + 4) ^ (kr & 7)) * 8]);  \
      a2 = __builtin_amdgcn_mfma_f32_16x16x32_bf16(kf0, qa0, a2, 0, 0, 0);             \
      a2 = __builtin_amdgcn_mfma_f32_16x16x32_bf16(kf1, qa1, a2, 0, 0, 0);             \
      float p0 = fexp2(a2[0]), p1 = fexp2(a2[1]);                                      \
      float p2 = fexp2(a2[2]), p3 = fexp2(a2[3]);                                      \
      pk[nt * 2]     = cvt_pk_bf16(p0, p1);                                            \
      pk[nt * 2 + 1] = cvt_pk_bf16(p2, p3);                                            \
    }                                                                                  \
    __builtin_amdgcn_s_setprio(0);                                                     \
    _Pragma("unroll")                                                                  \
    for (int i = 0; i < 4; i++) {                                                      \
      int chunk = 2 * i + (quad >> 1);                                                 \
      union { unsigned uu[2]; unsigned long long ll; } wrp;                            \
      wrp.uu[0] = pk[2 * i]; wrp.uu[1] = pk[2 * i + 1];                                \
      *(unsigned long long*)(pw + m16 * 64 + ((chunk ^ (m16 & 7)) << 3)                \
                             + (quad & 1) * 4) = wrp.ll;                               \
    }                                                                                  \
    bf16x8 pa0 = *(const bf16x8*)(pw + m16 * 64 + ((quad ^ (m16 & 7)) << 3));          \
    bf16x8 pa1 = *(const bf16x8*)(pw + m16 * 64 + (((quad + 4) ^ (m16 & 7)) << 3));    \
    __builtin_amdgcn_s_setprio(1);                                                     \
    rs = __builtin_amdgcn_mfma_f32_16x16x32_bf16(pa0, kones, rs, 0, 0, 0);             \
    rs = __builtin_amdgcn_mfma_f32_16x16x32_bf16(pa1, kones, rs, 0, 0, 0);             \
    _Pragma("unroll")                                                                  \
    for (int nt = 0; nt < 4; nt++) {                                                   \
      int d = nt * 16 + m16;                                                           \
      bf16x8 vf0 = *(const bf16x8*)(&Vs[buf][d * 64 + ((quad) ^ (d & 7)) * 8]);        \
      bf16x8 vf1 = *(const bf16x8*)(&Vs[buf][d * 64 + ((quad + 4) ^ (d & 7)) * 8]);    \
      o[nt] = __builtin_amdgcn_mfma_f32_16x16x32_bf16(pa0, vf0, o[nt], 0, 0, 0);       \
      o[nt] = __builtin_amdgcn_mfma_f32_16x16x32_bf16(pa1, vf1, o[nt], 0, 0, 0);       \
    }                                                                                  \
    __builtin_amdgcn_s_setprio(0);                                                     \
    if (jt + 1 < 32) {                                                                 \
      *(bf16x8*)(&Ks[buf ^ 1][soff]) = KCUR;                                           \
      *(bf16x8*)(&Vs[buf ^ 1][soff]) = VCUR;                                           \
    }                                                                                  \
    __syncthreads();                                                                   \
  }

__global__ __launch_bounds__(512, 4) void attn_mfma(const ushort_t* __restrict__ qb,
                                                    const ushort_t* __restrict__ kb,
                                                    const ushort_t* __restrict__ vb,
                                                    const ushort_t* __restrict__ bp,
                                                    ushort_t* __restrict__ attn) {
    __shared__ ushort_t Ks[2][64 * 64];      // [buf][key][d] swizzled, 8KB each
    __shared__ ushort_t Vs[2][64 * 64];      // [buf][d][key] swizzled, 8KB each
    __shared__ ushort_t p_s[8][16 * 64];     // [wave][qrow][key] swizzled, 16KB

    const int t = threadIdx.x;
    const int w = t >> 6, lane = t & 63;
    const int m16 = lane & 15, quad = lane >> 4;
    const int id = blockIdx.x;
    const int bh = id & 31;                  // XCD = id%8 = bh%8 (heuristic)
    const int qt = id >> 5;
    const int b = bh >> 3, h = bh & 7;
    const int n0w = qt * 128 + w * 16;

    // staging: thread stages exactly one 8-elem chunk of K and of V per tile
    const int srow = t >> 3, scb = t & 7;
    const int soff = srow * 64 + (scb ^ (srow & 7)) * 8;
    const ushort_t* kgbase = kb + ((size_t)bh * N_) * 64;   // [key][d]
    const ushort_t* vgbase = vb + ((size_t)bh * 64) * N_;   // [d][key]

    // Q frags (one 16-row m-frag per wave)
    const ushort_t* qpb = qb + ((size_t)(bh * N_ + n0w + m16)) * 64 + quad * 8;
    bf16x8 qa0 = *(const bf16x8*)(qpb);
    bf16x8 qa1 = *(const bf16x8*)(qpb + 32);

    // bias packed [qt][jt][w][nt][quad][m16][k4]; per phase the 16 m16-lanes read 128B contiguous
    const ushort_t* bpb = bp + ((size_t)qt << 18) + (w << 10) + (quad << 6) + (m16 << 2);

    // all-ones bf16 B-frag for the rowsum MFMA (layout-invariant)
    bf16x8 kones;
    #pragma unroll
    for (int i = 0; i < 8; i++) kones[i] = (short)0x3F80;

    // prologue: stage tile 0 into buf 0; prefetch tile 1 (regs) and bias jt=0 (regs)
    *(bf16x8*)(&Ks[0][soff]) = *(const bf16x8*)(kgbase + (size_t)srow * 64 + scb * 8);
    *(bf16x8*)(&Vs[0][soff]) = *(const bf16x8*)(vgbase + (size_t)srow * N_ + scb * 8);
    bf16x8 kA = *(const bf16x8*)(kgbase + (size_t)(64 + srow) * 64 + scb * 8);
    bf16x8 vA = *(const bf16x8*)(vgbase + (size_t)srow * N_ + 64 + scb * 8);
    bf16x8 kB, vB;
    bf16x4 bA[4], bB[4];
    #pragma unroll
    for (int nt = 0; nt < 4; nt++) bA[nt] = *(const bf16x4*)(bpb + (nt << 8));
    __syncthreads();

    f32x4 o[4];
    #pragma unroll
    for (int nt = 0; nt < 4; nt++) o[nt] = (f32x4){0.f, 0.f, 0.f, 0.f};
    f32x4 rs = (f32x4){0.f, 0.f, 0.f, 0.f};

    ushort_t* pw = p_s[w];

    for (int jt2 = 0; jt2 < 16; jt2++) {
        ATTN_TILE(2 * jt2,     kA, vA, kB, vB, bA, bB);
        ATTN_TILE(2 * jt2 + 1, kB, vB, kA, vA, bB, bA);
    }

    // ---- normalize + store: o[nt][r] is (qrow=quad*4+r, d=nt*16+m16); rs[r] = rowsum(qrow) ----
    #pragma unroll
    for (int r = 0; r < 4; r++) {
        float inv = 1.0f / rs[r];
        int n = n0w + quad * 4 + r;
        ushort_t* orow = attn + ((size_t)(b * N_ + n)) * 512 + h * 64 + m16;
        #pragma unroll
        for (int nt = 0; nt < 4; nt++) orow[nt * 16] = f2bf(o[nt][r] * inv);
    }
}

extern "C" void kernel_launch(void* const* d_in, const int* in_sizes, int n_in,
                              void* d_out, int out_size, void* d_ws, size_t ws_size,
                              hipStream_t stream) {
    const float* x     = (const float*)d_in[0];
    const float* gamma = (const float*)d_in[1];
    const float* beta  = (const float*)d_in[2];
    const float* Wqkv  = (const float*)d_in[3];
    const float* Wout  = (const float*)d_in[4];
    const float* bout  = (const float*)d_in[5];
    const float* rel   = (const float*)d_in[6];
    const int*   mask  = (const int*)d_in[7];
    float* out = (float*)d_out;

    char* wsb = (char*)d_ws;
    ushort_t* xn    = (ushort_t*)(wsb);                    //  8 MB
    ushort_t* attnb = (ushort_t*)(wsb + ( 8u << 20));      //  8 MB
    ushort_t* qb    = (ushort_t*)(wsb + (16u << 20));      //  8 MB
    ushort_t* kb    = (ushort_t*)(wsb + (24u << 20));      //  8 MB
    ushort_t* vb    = (ushort_t*)(wsb + (32u << 20));      //  8 MB
    ushort_t* WqkvT = (ushort_t*)(wsb + (40u << 20));      //  1.5 MB
    ushort_t* WoutT = (ushort_t*)(wsb + (42u << 20));      //  0.5 MB
    ushort_t* bp    = (ushort_t*)(wsb + (44u << 20));      //  8 MB

    // 1. prep: layernorm + both weight transposes
    prep_kernel<<<PREP_LN + PREP_WQ + PREP_WO, 256, 0, stream>>>(
        x, gamma, beta, xn, Wqkv, WqkvT, Wout, WoutT);

    // 2. QKV projection (8-wave pipelined MFMA, XCD-swizzled) + concurrent bias-pack blocks
    gemm_qkv<<<QKV_BIAS_BLKS + 768, 512, 0, stream>>>(xn, WqkvT, qb, kb, vb, rel, mask, bp);

    // 3. MFMA flash attention v11 -> bf16
    attn_mfma<<<512, 512, 0, stream>>>(qb, kb, vb, bp, attnb);

    // 4. output projection + bias (8-wave pipelined MFMA, XCD-swizzled) -> fp32
    gemm_out<<<512, 512, 0, stream>>>(attnb, WoutT, bout, out);
}